// Round 9
// baseline (397.803 us; speedup 1.0000x reference)
//
#include <hip/hip_runtime.h>
#include <hip/hip_bf16.h>
#include <hip/hip_cooperative_groups.h>

namespace cg = cooperative_groups;

#define DIMC   512
#define NHEADS 8
#define HD     64
#define Bb     2
#define Hh     32
#define Ww     32
#define Lq     1024          // H*W
#define BHW    2048          // B*H*W
#define KVH    16
#define KVW    16
#define Mkv    2048          // KVH*KVW*NHEADS
#define SL2E   0.18033688011112042f   // (1/8) * log2(e)
#define NC     4             // attention m-chunks (split-K)
#define NROWS  (Bb * NHEADS * Lq)     // 16384 partial rows

#if defined(__has_builtin)
#if __has_builtin(__builtin_amdgcn_exp2f)
#define EXP2(x) __builtin_amdgcn_exp2f(x)
#else
#define EXP2(x) exp2f(x)
#endif
#else
#define EXP2(x) exp2f(x)
#endif

typedef short bf16x8_t __attribute__((ext_vector_type(8)));
typedef float f32x4_t  __attribute__((ext_vector_type(4)));

__device__ __forceinline__ short f2bf(float f) {
    __hip_bfloat16 h = __float2bfloat16(f);
    return *reinterpret_cast<short*>(&h);
}
__device__ __forceinline__ float bf2f(short s) {
    unsigned u = ((unsigned)(unsigned short)s) << 16;
    return *reinterpret_cast<float*>(&u);
}

#define QTILE 32
#define MTILE 64
#define ITERS (Mkv / NC / MTILE)   // 8

// ============ cooperative mega-kernel, grid-size agnostic ==================
__global__ __launch_bounds__(256, 4) void mega_k(
    const float* __restrict__ x,  const float* __restrict__ wq,
    const float* __restrict__ bq, const float* __restrict__ wkv,
    const float* __restrict__ bkv,const float* __restrict__ dwk,
    const float* __restrict__ dwb,const float* __restrict__ wo,
    const float* __restrict__ bo, float* __restrict__ out,
    short* __restrict__ xb, short* __restrict__ wqkvT, short* __restrict__ woT,
    short* __restrict__ qb, short* __restrict__ Kbf, short* __restrict__ Vt,
    short* __restrict__ aob, float* __restrict__ kv,
    short* __restrict__ po, float* __restrict__ pl)
{
    cg::grid_group grid = cg::this_grid();
    __shared__ __align__(16) char smem[40960];
    const int bid = blockIdx.x;
    const int G   = gridDim.x;
    const int tid = threadIdx.x;
    const int w    = tid >> 6;
    const int lane = tid & 63;
    const int lr = lane & 15, lg = lane >> 4;

    // ---------------- stage 0: cast x + transpose weights ------------------
    {
        float (*t)[33] = reinterpret_cast<float(*)[33]>(smem);
        for (int job = bid; job < 1536; job += G) {
            if (job < 512) {
                const int i = job * 256 + tid;
                const float4 f0 = reinterpret_cast<const float4*>(x)[i * 2 + 0];
                const float4 f1 = reinterpret_cast<const float4*>(x)[i * 2 + 1];
                bf16x8_t v;
                v[0]=f2bf(f0.x); v[1]=f2bf(f0.y); v[2]=f2bf(f0.z); v[3]=f2bf(f0.w);
                v[4]=f2bf(f1.x); v[5]=f2bf(f1.y); v[6]=f2bf(f1.z); v[7]=f2bf(f1.w);
                reinterpret_cast<bf16x8_t*>(xb)[i] = v;
            } else {
                const int tt0 = job - 512;   // 0..1023
                const float* W; short* WT; int N, rbase, n0, k0;
                if (tt0 < 256)      { W = wq;  WT = wqkvT; N = DIMC;   rbase = 0;
                                      n0 = (tt0 & 15) * 32; k0 = (tt0 >> 4) * 32; }
                else if (tt0 < 768) { int u = tt0 - 256; W = wkv; WT = wqkvT;
                                      N = 2*DIMC; rbase = 512;
                                      n0 = (u & 31) * 32; k0 = (u >> 5) * 32; }
                else                { int u = tt0 - 768; W = wo;  WT = woT;
                                      N = DIMC; rbase = 0;
                                      n0 = (u & 15) * 32; k0 = (u >> 4) * 32; }
                const int c = tid & 31, r = tid >> 5;   // r 0..7
                __syncthreads();
                #pragma unroll
                for (int i = 0; i < 4; ++i)
                    t[r + 8 * i][c] = W[(size_t)(k0 + r + 8 * i) * N + n0 + c];
                __syncthreads();
                #pragma unroll
                for (int i = 0; i < 4; ++i)
                    WT[(size_t)(rbase + n0 + r + 8 * i) * DIMC + k0 + c] =
                        f2bf(t[c][r + 8 * i]);
            }
        }
    }
    grid.sync();

    // ---------------- stage 1: fused q/kv GEMM (768 tiles) -----------------
    for (int tile = bid; tile < 768; tile += G) {
        const int n0 = (tile % 24) * 64;
        const int m0 = (tile / 24) * 64 + w * 16;
        const short* Arow = xb    + (size_t)(m0 + lr) * DIMC + lg * 8;
        const short* Brow = wqkvT + (size_t)(n0 + lr) * DIMC + lg * 8;

        f32x4_t acc[4];
        #pragma unroll
        for (int nt = 0; nt < 4; ++nt) acc[nt] = f32x4_t{0.f,0.f,0.f,0.f};

        bf16x8_t a0 = *reinterpret_cast<const bf16x8_t*>(Arow);
        bf16x8_t b0[4];
        #pragma unroll
        for (int nt = 0; nt < 4; ++nt)
            b0[nt] = *reinterpret_cast<const bf16x8_t*>(Brow + nt * 16 * DIMC);

        #pragma unroll
        for (int k0 = 0; k0 < 480; k0 += 32) {
            bf16x8_t a1 = *reinterpret_cast<const bf16x8_t*>(Arow + k0 + 32);
            bf16x8_t b1[4];
            #pragma unroll
            for (int nt = 0; nt < 4; ++nt)
                b1[nt] = *reinterpret_cast<const bf16x8_t*>(Brow + nt*16*DIMC + k0 + 32);
            #pragma unroll
            for (int nt = 0; nt < 4; ++nt)
                acc[nt] = __builtin_amdgcn_mfma_f32_16x16x32_bf16(a0, b0[nt], acc[nt], 0,0,0);
            a0 = a1;
            #pragma unroll
            for (int nt = 0; nt < 4; ++nt) b0[nt] = b1[nt];
        }
        #pragma unroll
        for (int nt = 0; nt < 4; ++nt)
            acc[nt] = __builtin_amdgcn_mfma_f32_16x16x32_bf16(a0, b0[nt], acc[nt], 0,0,0);

        if (n0 < 512) {
            #pragma unroll
            for (int nt = 0; nt < 4; ++nt) {
                const int col = n0 + nt * 16 + lr;
                const float bv = bq[col];
                #pragma unroll
                for (int j = 0; j < 4; ++j)
                    qb[(size_t)(m0 + lg*4 + j) * DIMC + col] = f2bf(acc[nt][j] + bv);
            }
        } else {
            #pragma unroll
            for (int nt = 0; nt < 4; ++nt) {
                const int col = n0 - 512 + nt * 16 + lr;
                const float bv = bkv[col];
                #pragma unroll
                for (int j = 0; j < 4; ++j)
                    kv[(size_t)(m0 + lg*4 + j) * 1024 + col] = acc[nt][j] + bv;
            }
        }
    }
    grid.sync();

    // ---------------- stage 2: depthwise conv (2048 chunks) ----------------
    for (int chunk = bid; chunk < 2048; chunk += G) {
        const int idx = chunk * 256 + tid;
        const int c  = idx & 1023;
        const int ow = (idx >> 10) & 15;
        const int oh = (idx >> 14) & 15;
        const int b  = idx >> 18;
        float acc = dwb[c];
        #pragma unroll
        for (int kh = 0; kh < 3; ++kh) {
            int ih = oh * 2 + kh;
            if (ih >= Hh) continue;
            #pragma unroll
            for (int kw = 0; kw < 3; ++kw) {
                int iw = ow * 2 + kw;
                if (iw >= Ww) continue;
                acc += kv[(((size_t)b * Hh + ih) * Ww + iw) * 1024 + c]
                     * dwk[(kh * 3 + kw) * 1024 + c];
            }
        }
        const int s = oh * KVW + ow;
        if (c < 512) {
            int d = c & 63, ck = c >> 6;
            Kbf[((size_t)b * Mkv + s * 8 + ck) * HD + d] = f2bf(acc);
        } else {
            int c2 = c - 512;
            int d = c2 & 63, ck = c2 >> 6;
            Vt[((size_t)b * HD + d) * Mkv + s * 8 + ck] = f2bf(acc);
        }
    }
    grid.sync();

    // ---------------- stage 3: flash attention (2048 jobs, 2 subs/block) ---
    {
        const int sub  = tid >> 7;            // 2 sub-blocks of 128 threads
        const int stid = tid & 127;
        const int sw   = stid >> 6;
        const int slane= stid & 63;
        const int slr = slane & 15, slg = slane >> 4;
        char* sbase = smem + sub * 20480;
        char* Kl = sbase;
        char* Vl = sbase + 8192;
        char* Pl = sbase + 16384 + sw * 2048;
        const int Lr8 = slane >> 3;
        const int jc  = slane & 7;

        // jobs come in pairs (stride even) -> both subs always in lockstep
        for (int jobbase = bid * 2; jobbase < 2048; jobbase += G * 2) {
            const int job   = jobbase + sub;
            const int bid0  = job & 511;
            const int chunk = job >> 9;
            const int qt  = bid0 & 31;
            const int n   = (bid0 >> 5) & 7;
            const int b   = bid0 >> 8;
            const int q0  = qt * QTILE + sw * 16;

            bf16x8_t qf[2];
            {
                const short* qrow = qb + ((size_t)(b * Lq) + q0 + slr) * DIMC + n * HD + slg * 8;
                #pragma unroll
                for (int ks = 0; ks < 2; ++ks) {
                    bf16x8_t t = *reinterpret_cast<const bf16x8_t*>(qrow + ks * 32);
                    #pragma unroll
                    for (int j = 0; j < 8; ++j) t[j] = f2bf(bf2f(t[j]) * SL2E);
                    qf[ks] = t;
                }
            }

            f32x4_t o[4];
            #pragma unroll
            for (int dt = 0; dt < 4; ++dt) o[dt] = f32x4_t{0.f,0.f,0.f,0.f};
            float lacc[4] = {0.f,0.f,0.f,0.f};

            const short* Kb = Kbf + (size_t)b * Mkv * HD;
            const short* Vb = Vt  + (size_t)b * HD * Mkv;
            const int mbase = chunk * (Mkv / NC);

            bf16x8_t kreg[4], vreg[4];
            auto load_tile = [&](int mt) {
                #pragma unroll
                for (int c4 = 0; c4 < 4; ++c4) {
                    const int row = c4 * 16 + sw * 8 + Lr8;
                    kreg[c4] = *reinterpret_cast<const bf16x8_t*>(
                        Kb + (size_t)(mt + row) * HD + jc * 8);
                    vreg[c4] = *reinterpret_cast<const bf16x8_t*>(
                        Vb + (size_t)row * Mkv + mt + jc * 8);
                }
            };
            auto write_tile = [&]() {
                #pragma unroll
                for (int c4 = 0; c4 < 4; ++c4) {
                    const int row = c4 * 16 + sw * 8 + Lr8;
                    const int off = row * 128 + ((jc * 16) ^ ((row & 7) << 4));
                    *reinterpret_cast<bf16x8_t*>(Kl + off) = kreg[c4];
                    *reinterpret_cast<bf16x8_t*>(Vl + off) = vreg[c4];
                }
            };

            load_tile(mbase);

            for (int it = 0; it < ITERS; ++it) {
                write_tile();
                __syncthreads();
                if (it < ITERS - 1) load_tile(mbase + (it + 1) * MTILE);

                f32x4_t s[4];
                __builtin_amdgcn_s_setprio(1);
                #pragma unroll
                for (int nt = 0; nt < 4; ++nt) {
                    const int ml = nt * 16 + slr;
                    f32x4_t acc = f32x4_t{0.f,0.f,0.f,0.f};
                    bf16x8_t k0 = *reinterpret_cast<bf16x8_t*>(
                        Kl + ml * 128 + ((slg * 16)      ^ ((ml & 7) << 4)));
                    bf16x8_t k1 = *reinterpret_cast<bf16x8_t*>(
                        Kl + ml * 128 + ((64 + slg * 16) ^ ((ml & 7) << 4)));
                    acc = __builtin_amdgcn_mfma_f32_16x16x32_bf16(qf[0], k0, acc, 0,0,0);
                    acc = __builtin_amdgcn_mfma_f32_16x16x32_bf16(qf[1], k1, acc, 0,0,0);
                    s[nt] = acc;
                }
                __builtin_amdgcn_s_setprio(0);
                #pragma unroll
                for (int nt = 0; nt < 4; ++nt)
                    #pragma unroll
                    for (int r = 0; r < 4; ++r) {
                        float p = EXP2(s[nt][r]);
                        s[nt][r] = p;
                        lacc[r] += p;
                    }

                #pragma unroll
                for (int nt = 0; nt < 4; ++nt)
                    #pragma unroll
                    for (int r = 0; r < 4; ++r) {
                        const int qL = slg * 4 + r;
                        const int mL = nt * 16 + slr;
                        *reinterpret_cast<short*>(
                            Pl + qL * 128 + ((mL * 2) ^ ((qL & 7) << 4))) = f2bf(s[nt][r]);
                    }

                bf16x8_t pf[2];
                #pragma unroll
                for (int ks2 = 0; ks2 < 2; ++ks2)
                    pf[ks2] = *reinterpret_cast<bf16x8_t*>(
                        Pl + slr * 128 + ((ks2 * 64 + slg * 16) ^ ((slr & 7) << 4)));
                __builtin_amdgcn_s_setprio(1);
                #pragma unroll
                for (int dt = 0; dt < 4; ++dt) {
                    const int dL = dt * 16 + slr;
                    #pragma unroll
                    for (int ks2 = 0; ks2 < 2; ++ks2) {
                        bf16x8_t vb = *reinterpret_cast<bf16x8_t*>(
                            Vl + dL * 128 + ((ks2 * 64 + slg * 16) ^ ((dL & 7) << 4)));
                        o[dt] = __builtin_amdgcn_mfma_f32_16x16x32_bf16(pf[ks2], vb, o[dt], 0,0,0);
                    }
                }
                __builtin_amdgcn_s_setprio(0);
                __syncthreads();
            }

            #pragma unroll
            for (int r = 0; r < 4; ++r) {
                float l = lacc[r];
                l += __shfl_xor(l, 1);
                l += __shfl_xor(l, 2);
                l += __shfl_xor(l, 4);
                l += __shfl_xor(l, 8);
                const float inv = 1.0f / l;
                const int grow = ((b * NHEADS + n) << 10) + q0 + slg * 4 + r;
                #pragma unroll
                for (int dt = 0; dt < 4; ++dt)
                    po[((size_t)chunk * NROWS + grow) * HD + dt * 16 + slr] =
                        f2bf(o[dt][r] * inv);
                if (slr == 0) pl[chunk * NROWS + grow] = l;
            }
        }
    }
    grid.sync();

    // ---------------- stage 4: combine partials (512 chunks) ---------------
    for (int chunk = bid; chunk < 512; chunk += G) {
        const int idx = chunk * 256 + tid;
        const int grow = idx >> 3, dc = idx & 7;
        float l[NC], lsum = 0.f;
        #pragma unroll
        for (int c = 0; c < NC; ++c) { l[c] = pl[c * NROWS + grow]; lsum += l[c]; }
        float num[8] = {};
        #pragma unroll
        for (int c = 0; c < NC; ++c) {
            bf16x8_t v = *reinterpret_cast<const bf16x8_t*>(
                po + ((size_t)c * NROWS + grow) * HD + dc * 8);
            #pragma unroll
            for (int j = 0; j < 8; ++j) num[j] += l[c] * bf2f(v[j]);
        }
        const float inv = 1.0f / lsum;
        bf16x8_t r;
        #pragma unroll
        for (int j = 0; j < 8; ++j) r[j] = f2bf(num[j] * inv);
        const int b = grow >> 13, n = (grow >> 10) & 7, qrow = grow & 1023;
        *reinterpret_cast<bf16x8_t*>(
            aob + ((size_t)((b << 10) + qrow)) * DIMC + (n << 6) + dc * 8) = r;
    }
    grid.sync();

    // ---------------- stage 5: out GEMM (512 tiles of 32x64) ---------------
    for (int tile = bid; tile < 512; tile += G) {
        const int wm = w & 1, wn = w >> 1;
        const int m0 = (tile >> 3) * 32 + wm * 16;
        const int n0 = (tile & 7) * 64 + wn * 32;
        const short* Arow = aob + (size_t)(m0 + lr) * DIMC + lg * 8;
        const short* Brow = woT + (size_t)(n0 + lr) * DIMC + lg * 8;

        f32x4_t acc[2];
        acc[0] = f32x4_t{0.f,0.f,0.f,0.f};
        acc[1] = f32x4_t{0.f,0.f,0.f,0.f};

        bf16x8_t a0 = *reinterpret_cast<const bf16x8_t*>(Arow);
        bf16x8_t b0[2];
        b0[0] = *reinterpret_cast<const bf16x8_t*>(Brow);
        b0[1] = *reinterpret_cast<const bf16x8_t*>(Brow + 16 * DIMC);

        #pragma unroll
        for (int k0 = 0; k0 < 480; k0 += 32) {
            bf16x8_t a1 = *reinterpret_cast<const bf16x8_t*>(Arow + k0 + 32);
            bf16x8_t b1[2];
            b1[0] = *reinterpret_cast<const bf16x8_t*>(Brow + k0 + 32);
            b1[1] = *reinterpret_cast<const bf16x8_t*>(Brow + 16 * DIMC + k0 + 32);
            acc[0] = __builtin_amdgcn_mfma_f32_16x16x32_bf16(a0, b0[0], acc[0], 0,0,0);
            acc[1] = __builtin_amdgcn_mfma_f32_16x16x32_bf16(a0, b0[1], acc[1], 0,0,0);
            a0 = a1; b0[0] = b1[0]; b0[1] = b1[1];
        }
        acc[0] = __builtin_amdgcn_mfma_f32_16x16x32_bf16(a0, b0[0], acc[0], 0,0,0);
        acc[1] = __builtin_amdgcn_mfma_f32_16x16x32_bf16(a0, b0[1], acc[1], 0,0,0);

        #pragma unroll
        for (int nt = 0; nt < 2; ++nt) {
            const int col = n0 + nt * 16 + lr;
            const float bv = bo[col];
            #pragma unroll
            for (int j = 0; j < 4; ++j)
                out[(size_t)(m0 + lg * 4 + j) * DIMC + col] = acc[nt][j] + bv;
        }
    }
}

// ===================== fallback kernels (R7, proven) =======================
__global__ __launch_bounds__(256) void prep_k(
    const float* __restrict__ x, short* __restrict__ xb,
    const float* __restrict__ wq, const float* __restrict__ wkv,
    const float* __restrict__ wo, short* __restrict__ wqkvT,
    short* __restrict__ woT)
{
    const int z = blockIdx.z;
    if (z == 0) {
        const int i = (blockIdx.y * 32 + blockIdx.x) * 256 + threadIdx.x;
        const float4 f0 = reinterpret_cast<const float4*>(x)[i * 2 + 0];
        const float4 f1 = reinterpret_cast<const float4*>(x)[i * 2 + 1];
        bf16x8_t t;
        t[0]=f2bf(f0.x); t[1]=f2bf(f0.y); t[2]=f2bf(f0.z); t[3]=f2bf(f0.w);
        t[4]=f2bf(f1.x); t[5]=f2bf(f1.y); t[6]=f2bf(f1.z); t[7]=f2bf(f1.w);
        reinterpret_cast<bf16x8_t*>(xb)[i] = t;
        return;
    }
    const float* W; short* WT; int N, rbase;
    if (z == 1)      { W = wq;  WT = wqkvT; N = DIMC;     rbase = 0;   }
    else if (z == 2) { W = wkv; WT = wqkvT; N = 2 * DIMC; rbase = 512; }
    else             { W = wo;  WT = woT;   N = DIMC;     rbase = 0;   }
    const int n0 = blockIdx.x * 32, k0 = blockIdx.y * 32;
    if (n0 >= N) return;
    __shared__ float t[32][33];
    const int c = threadIdx.x & 31, r = threadIdx.x >> 5;
    #pragma unroll
    for (int i = 0; i < 4; ++i)
        t[r + 8 * i][c] = W[(size_t)(k0 + r + 8 * i) * N + n0 + c];
    __syncthreads();
    #pragma unroll
    for (int i = 0; i < 4; ++i)
        WT[(size_t)(rbase + n0 + r + 8 * i) * DIMC + k0 + c] = f2bf(t[c][r + 8 * i]);
}

__global__ __launch_bounds__(256) void gemm_qkv_k(
    const short* __restrict__ A, const short* __restrict__ WT,
    const float* __restrict__ bq, const float* __restrict__ bkv,
    short* __restrict__ qb, float* __restrict__ kv)
{
    const int tid = threadIdx.x, w = tid >> 6, lane = tid & 63;
    const int lr = lane & 15, lg = lane >> 4;
    const int m0 = blockIdx.y * 64 + w * 16;
    const int n0 = blockIdx.x * 64;
    const short* Arow = A  + (size_t)(m0 + lr) * DIMC + lg * 8;
    const short* Brow = WT + (size_t)(n0 + lr) * DIMC + lg * 8;
    f32x4_t acc[4];
    #pragma unroll
    for (int nt = 0; nt < 4; ++nt) acc[nt] = f32x4_t{0.f,0.f,0.f,0.f};
    bf16x8_t a0 = *reinterpret_cast<const bf16x8_t*>(Arow);
    bf16x8_t b0[4];
    #pragma unroll
    for (int nt = 0; nt < 4; ++nt)
        b0[nt] = *reinterpret_cast<const bf16x8_t*>(Brow + nt * 16 * DIMC);
    #pragma unroll
    for (int k0 = 0; k0 < 480; k0 += 32) {
        bf16x8_t a1 = *reinterpret_cast<const bf16x8_t*>(Arow + k0 + 32);
        bf16x8_t b1[4];
        #pragma unroll
        for (int nt = 0; nt < 4; ++nt)
            b1[nt] = *reinterpret_cast<const bf16x8_t*>(Brow + nt*16*DIMC + k0 + 32);
        #pragma unroll
        for (int nt = 0; nt < 4; ++nt)
            acc[nt] = __builtin_amdgcn_mfma_f32_16x16x32_bf16(a0, b0[nt], acc[nt], 0,0,0);
        a0 = a1;
        #pragma unroll
        for (int nt = 0; nt < 4; ++nt) b0[nt] = b1[nt];
    }
    #pragma unroll
    for (int nt = 0; nt < 4; ++nt)
        acc[nt] = __builtin_amdgcn_mfma_f32_16x16x32_bf16(a0, b0[nt], acc[nt], 0,0,0);
    if (n0 < 512) {
        #pragma unroll
        for (int nt = 0; nt < 4; ++nt) {
            const int col = n0 + nt * 16 + lr;
            const float bv = bq[col];
            #pragma unroll
            for (int j = 0; j < 4; ++j)
                qb[(size_t)(m0 + lg*4 + j) * DIMC + col] = f2bf(acc[nt][j] + bv);
        }
    } else {
        #pragma unroll
        for (int nt = 0; nt < 4; ++nt) {
            const int col = n0 - 512 + nt * 16 + lr;
            const float bv = bkv[col];
            #pragma unroll
            for (int j = 0; j < 4; ++j)
                kv[(size_t)(m0 + lg*4 + j) * 1024 + col] = acc[nt][j] + bv;
        }
    }
}

__global__ __launch_bounds__(512) void gemm_out_k(
    const short* __restrict__ A, const short* __restrict__ WT,
    const float* __restrict__ bo, float* __restrict__ C)
{
    const int tid = threadIdx.x, w = tid >> 6, lane = tid & 63;
    const int lr = lane & 15, lg = lane >> 4;
    const int wm = w >> 1, wn = w & 1;
    const int m0 = blockIdx.y * 64 + wm * 16;
    const int n0 = blockIdx.x * 64 + wn * 32;
    const short* Arow = A  + (size_t)(m0 + lr) * DIMC + lg * 8;
    const short* Brow = WT + (size_t)(n0 + lr) * DIMC + lg * 8;
    f32x4_t acc[2];
    acc[0] = f32x4_t{0.f,0.f,0.f,0.f};
    acc[1] = f32x4_t{0.f,0.f,0.f,0.f};
    bf16x8_t a0 = *reinterpret_cast<const bf16x8_t*>(Arow);
    bf16x8_t b0[2];
    b0[0] = *reinterpret_cast<const bf16x8_t*>(Brow);
    b0[1] = *reinterpret_cast<const bf16x8_t*>(Brow + 16 * DIMC);
    #pragma unroll
    for (int k0 = 0; k0 < 480; k0 += 32) {
        bf16x8_t a1 = *reinterpret_cast<const bf16x8_t*>(Arow + k0 + 32);
        bf16x8_t b1[2];
        b1[0] = *reinterpret_cast<const bf16x8_t*>(Brow + k0 + 32);
        b1[1] = *reinterpret_cast<const bf16x8_t*>(Brow + 16 * DIMC + k0 + 32);
        acc[0] = __builtin_amdgcn_mfma_f32_16x16x32_bf16(a0, b0[0], acc[0], 0,0,0);
        acc[1] = __builtin_amdgcn_mfma_f32_16x16x32_bf16(a0, b0[1], acc[1], 0,0,0);
        a0 = a1; b0[0] = b1[0]; b0[1] = b1[1];
    }
    acc[0] = __builtin_amdgcn_mfma_f32_16x16x32_bf16(a0, b0[0], acc[0], 0,0,0);
    acc[1] = __builtin_amdgcn_mfma_f32_16x16x32_bf16(a0, b0[1], acc[1], 0,0,0);
    #pragma unroll
    for (int nt = 0; nt < 2; ++nt) {
        const int col = n0 + nt * 16 + lr;
        const float bv = bo[col];
        #pragma unroll
        for (int j = 0; j < 4; ++j)
            C[(size_t)(m0 + lg * 4 + j) * DIMC + col] = acc[nt][j] + bv;
    }
}

__global__ __launch_bounds__(256) void dwconv_k(
    const float* __restrict__ kv, const float* __restrict__ kern,
    const float* __restrict__ dbias, short* __restrict__ Kbf,
    short* __restrict__ Vt)
{
    int idx = blockIdx.x * 256 + threadIdx.x;
    const int c  = idx & 1023;
    const int ow = (idx >> 10) & 15;
    const int oh = (idx >> 14) & 15;
    const int b  = idx >> 18;
    float acc = dbias[c];
    #pragma unroll
    for (int kh = 0; kh < 3; ++kh) {
        int ih = oh * 2 + kh;
        if (ih >= Hh) continue;
        #pragma unroll
        for (int kw = 0; kw < 3; ++kw) {
            int iw = ow * 2 + kw;
            if (iw >= Ww) continue;
            acc += kv[(((size_t)b * Hh + ih) * Ww + iw) * 1024 + c]
                 * kern[(kh * 3 + kw) * 1024 + c];
        }
    }
    const int s = oh * KVW + ow;
    if (c < 512) {
        int d = c & 63, ck = c >> 6;
        Kbf[((size_t)b * Mkv + s * 8 + ck) * HD + d] = f2bf(acc);
    } else {
        int c2 = c - 512;
        int d = c2 & 63, ck = c2 >> 6;
        Vt[((size_t)b * HD + d) * Mkv + s * 8 + ck] = f2bf(acc);
    }
}

__global__ __launch_bounds__(128) void attn_mfma_k(
    const short* __restrict__ qb, const short* __restrict__ K,
    const short* __restrict__ Vt, short* __restrict__ po,
    float* __restrict__ pl)
{
    __shared__ __align__(16) char smem[20480];
    char* Kl = smem;
    char* Vl = smem + 8192;
    const int tid  = threadIdx.x;
    const int w    = tid >> 6;
    const int lane = tid & 63;
    char* Pl = smem + 16384 + w * 2048;
    const int bid = blockIdx.x;
    const int chunk = blockIdx.y;
    const int qt  = bid & 31;
    const int n   = (bid >> 5) & 7;
    const int b   = bid >> 8;
    const int q0  = qt * QTILE + w * 16;
    const int lr = lane & 15;
    const int lg = lane >> 4;
    bf16x8_t qf[2];
    {
        const short* qrow = qb + ((size_t)(b * Lq) + q0 + lr) * DIMC + n * HD + lg * 8;
        #pragma unroll
        for (int ks = 0; ks < 2; ++ks) {
            bf16x8_t t = *reinterpret_cast<const bf16x8_t*>(qrow + ks * 32);
            #pragma unroll
            for (int j = 0; j < 8; ++j) t[j] = f2bf(bf2f(t[j]) * SL2E);
            qf[ks] = t;
        }
    }
    f32x4_t o[4];
    #pragma unroll
    for (int dt = 0; dt < 4; ++dt) o[dt] = f32x4_t{0.f,0.f,0.f,0.f};
    float lacc[4] = {0.f,0.f,0.f,0.f};
    const short* Kb = K  + (size_t)b * Mkv * HD;
    const short* Vb = Vt + (size_t)b * HD * Mkv;
    const int mbase = chunk * (Mkv / NC);
    const int Lr8 = lane >> 3;
    const int jj  = lane & 7;
    bf16x8_t kreg[4], vreg[4];
    auto load_tile = [&](int mt) {
        #pragma unroll
        for (int c = 0; c < 4; ++c) {
            const int row = c * 16 + w * 8 + Lr8;
            kreg[c] = *reinterpret_cast<const bf16x8_t*>(
                Kb + (size_t)(mt + row) * HD + jj * 8);
            vreg[c] = *reinterpret_cast<const bf16x8_t*>(
                Vb + (size_t)row * Mkv + mt + jj * 8);
        }
    };
    auto write_tile = [&]() {
        #pragma unroll
        for (int c = 0; c < 4; ++c) {
            const int row = c * 16 + w * 8 + Lr8;
            const int off = row * 128 + ((jj * 16) ^ ((row & 7) << 4));
            *reinterpret_cast<bf16x8_t*>(Kl + off) = kreg[c];
            *reinterpret_cast<bf16x8_t*>(Vl + off) = vreg[c];
        }
    };
    load_tile(mbase);
    for (int it = 0; it < ITERS; ++it) {
        write_tile();
        __syncthreads();
        if (it < ITERS - 1) load_tile(mbase + (it + 1) * MTILE);
        f32x4_t s[4];
        __builtin_amdgcn_s_setprio(1);
        #pragma unroll
        for (int nt = 0; nt < 4; ++nt) {
            const int ml = nt * 16 + lr;
            f32x4_t acc = f32x4_t{0.f,0.f,0.f,0.f};
            bf16x8_t k0 = *reinterpret_cast<bf16x8_t*>(
                Kl + ml * 128 + ((lg * 16)      ^ ((ml & 7) << 4)));
            bf16x8_t k1 = *reinterpret_cast<bf16x8_t*>(
                Kl + ml * 128 + ((64 + lg * 16) ^ ((ml & 7) << 4)));
            acc = __builtin_amdgcn_mfma_f32_16x16x32_bf16(qf[0], k0, acc, 0,0,0);
            acc = __builtin_amdgcn_mfma_f32_16x16x32_bf16(qf[1], k1, acc, 0,0,0);
            s[nt] = acc;
        }
        __builtin_amdgcn_s_setprio(0);
        #pragma unroll
        for (int nt = 0; nt < 4; ++nt)
            #pragma unroll
            for (int r = 0; r < 4; ++r) {
                float p = EXP2(s[nt][r]);
                s[nt][r] = p;
                lacc[r] += p;
            }
        #pragma unroll
        for (int nt = 0; nt < 4; ++nt)
            #pragma unroll
            for (int r = 0; r < 4; ++r) {
                const int qL = lg * 4 + r;
                const int mL = nt * 16 + lr;
                *reinterpret_cast<short*>(
                    Pl + qL * 128 + ((mL * 2) ^ ((qL & 7) << 4))) = f2bf(s[nt][r]);
            }
        bf16x8_t pf[2];
        #pragma unroll
        for (int ks2 = 0; ks2 < 2; ++ks2)
            pf[ks2] = *reinterpret_cast<bf16x8_t*>(
                Pl + lr * 128 + ((ks2 * 64 + lg * 16) ^ ((lr & 7) << 4)));
        __builtin_amdgcn_s_setprio(1);
        #pragma unroll
        for (int dt = 0; dt < 4; ++dt) {
            const int dL = dt * 16 + lr;
            #pragma unroll
            for (int ks2 = 0; ks2 < 2; ++ks2) {
                bf16x8_t vb = *reinterpret_cast<bf16x8_t*>(
                    Vl + dL * 128 + ((ks2 * 64 + lg * 16) ^ ((dL & 7) << 4)));
                o[dt] = __builtin_amdgcn_mfma_f32_16x16x32_bf16(pf[ks2], vb, o[dt], 0,0,0);
            }
        }
        __builtin_amdgcn_s_setprio(0);
        __syncthreads();
    }
    #pragma unroll
    for (int r = 0; r < 4; ++r) {
        float l = lacc[r];
        l += __shfl_xor(l, 1);
        l += __shfl_xor(l, 2);
        l += __shfl_xor(l, 4);
        l += __shfl_xor(l, 8);
        const float inv = 1.0f / l;
        const int grow = ((b * NHEADS + n) << 10) + q0 + lg * 4 + r;
        #pragma unroll
        for (int dt = 0; dt < 4; ++dt)
            po[((size_t)chunk * NROWS + grow) * HD + dt * 16 + lr] = f2bf(o[dt][r] * inv);
        if (lr == 0) pl[chunk * NROWS + grow] = l;
    }
}

__global__ __launch_bounds__(256) void attn_combine_k(
    const short* __restrict__ po, const float* __restrict__ pl,
    short* __restrict__ aob)
{
    const int idx = blockIdx.x * 256 + threadIdx.x;
    const int grow = idx >> 3, dc = idx & 7;
    float l[NC], lsum = 0.f;
    #pragma unroll
    for (int c = 0; c < NC; ++c) { l[c] = pl[c * NROWS + grow]; lsum += l[c]; }
    float num[8] = {};
    #pragma unroll
    for (int c = 0; c < NC; ++c) {
        bf16x8_t v = *reinterpret_cast<const bf16x8_t*>(
            po + ((size_t)c * NROWS + grow) * HD + dc * 8);
        #pragma unroll
        for (int j = 0; j < 8; ++j) num[j] += l[c] * bf2f(v[j]);
    }
    const float inv = 1.0f / lsum;
    bf16x8_t r;
    #pragma unroll
    for (int j = 0; j < 8; ++j) r[j] = f2bf(num[j] * inv);
    const int b = grow >> 13, n = (grow >> 10) & 7, qrow = grow & 1023;
    *reinterpret_cast<bf16x8_t*>(
        aob + ((size_t)((b << 10) + qrow)) * DIMC + (n << 6) + dc * 8) = r;
}

extern "C" void kernel_launch(void* const* d_in, const int* in_sizes, int n_in,
                              void* d_out, int out_size, void* d_ws, size_t ws_size,
                              hipStream_t stream)
{
    const float* x    = (const float*)d_in[0];
    const float* wq   = (const float*)d_in[1];
    const float* bq   = (const float*)d_in[2];
    const float* wkv  = (const float*)d_in[3];
    const float* bkv  = (const float*)d_in[4];
    const float* dwk  = (const float*)d_in[5];
    const float* dwb  = (const float*)d_in[6];
    const float* wo   = (const float*)d_in[7];
    const float* bo   = (const float*)d_in[8];
    float* out = (float*)d_out;

    float* kv_ws = (float*)d_ws;                          // 2048*1024 f32
    short* xb    = (short*)(kv_ws + (size_t)BHW * 1024);  // 2048*512
    short* wqkvT = xb    + (size_t)BHW * DIMC;            // 1536*512
    short* woT   = wqkvT + (size_t)3 * DIMC * DIMC;       // 512*512
    short* qb    = woT   + (size_t)DIMC * DIMC;           // 2048*512
    short* Kbf   = qb    + (size_t)BHW * DIMC;            // 2*2048*64
    short* Vt    = Kbf   + (size_t)Bb * Mkv * HD;         // 2*64*2048
    short* aob   = Vt    + (size_t)Bb * HD * Mkv;         // 2048*512
    short* po    = (short*)d_ws;                          // overlays kv_ws
    float* pl    = (float*)(po + (size_t)NC * NROWS * HD);// overlays xb

    // size the cooperative grid to what the runtime will actually accept
    int nb = 0;
    hipError_t qe = hipOccupancyMaxActiveBlocksPerMultiprocessor(
        &nb, (const void*)mega_k, 256, 0);
    hipError_t le = hipErrorUnknown;
    if (qe == hipSuccess && nb > 0) {
        int grid = nb * 256;           // 256 CUs on MI355X
        if (grid > 1024) grid = 1024;
        void* kargs[] = {
            (void*)&x, (void*)&wq, (void*)&bq, (void*)&wkv, (void*)&bkv,
            (void*)&dwk, (void*)&dwb, (void*)&wo, (void*)&bo, (void*)&out,
            (void*)&xb, (void*)&wqkvT, (void*)&woT, (void*)&qb, (void*)&Kbf,
            (void*)&Vt, (void*)&aob, (void*)&kv_ws, (void*)&po, (void*)&pl
        };
        le = hipLaunchCooperativeKernel((const void*)mega_k, dim3(grid),
                                        dim3(256), kargs, 0, stream);
    }
    if (le != hipSuccess) {
        // fallback: proven 6-kernel pipeline
        prep_k<<<dim3(32, 16, 4), 256, 0, stream>>>(x, xb, wq, wkv, wo, wqkvT, woT);
        gemm_qkv_k<<<dim3(24, 32), 256, 0, stream>>>(xb, wqkvT, bq, bkv, qb, kv_ws);
        dwconv_k<<<(Bb * KVH * KVW * 1024) / 256, 256, 0, stream>>>(
            kv_ws, dwk, dwb, Kbf, Vt);
        attn_mfma_k<<<dim3(Bb * NHEADS * (Lq / QTILE), NC), 128, 0, stream>>>(
            qb, Kbf, Vt, po, pl);
        attn_combine_k<<<NROWS * 8 / 256, 256, 0, stream>>>(po, pl, aob);
        gemm_out_k<<<dim3(8, 32), 512, 0, stream>>>(aob, woT, bo, out);
    }
}

// Round 10
// 94.274 us; speedup vs baseline: 4.2196x; 4.2196x over previous
//
#include <hip/hip_runtime.h>
#include <hip/hip_bf16.h>

#define DIMC   512
#define NHEADS 8
#define HD     64
#define Bb     2
#define Hh     32
#define Ww     32
#define Lq     1024          // H*W
#define BHW    2048          // B*H*W
#define KVH    16
#define KVW    16
#define Mkv    2048          // KVH*KVW*NHEADS
#define SL2E   0.18033688011112042f   // (1/8) * log2(e)
#define NC     8             // attention m-chunks (split-K)
#define NROWS  (Bb * NHEADS * Lq)     // 16384 partial rows

typedef short bf16x8_t __attribute__((ext_vector_type(8)));
typedef float f32x4_t  __attribute__((ext_vector_type(4)));

__device__ __forceinline__ short f2bf(float f) {
    __hip_bfloat16 h = __float2bfloat16(f);
    return *reinterpret_cast<short*>(&h);
}
__device__ __forceinline__ float bf2f(short s) {
    unsigned u = ((unsigned)(unsigned short)s) << 16;
    return *reinterpret_cast<float*>(&u);
}

#define QTILE 32
#define MTILE 64
#define ITERS (Mkv / NC / MTILE)   // 4

// ------- prep: transpose wq/wkv/wo -> bf16 [N][K] --------------------------
__global__ __launch_bounds__(256) void prep_k(
    const float* __restrict__ wq, const float* __restrict__ wkv,
    const float* __restrict__ wo, short* __restrict__ wqkvT,
    short* __restrict__ woT)
{
    const int z = blockIdx.z;
    const float* W; short* WT; int N, rbase;
    if (z == 0)      { W = wq;  WT = wqkvT; N = DIMC;     rbase = 0;   }
    else if (z == 1) { W = wkv; WT = wqkvT; N = 2 * DIMC; rbase = 512; }
    else             { W = wo;  WT = woT;   N = DIMC;     rbase = 0;   }
    const int n0 = blockIdx.x * 32, k0 = blockIdx.y * 32;
    if (n0 >= N) return;
    __shared__ float t[32][33];
    const int c = threadIdx.x & 31, r = threadIdx.x >> 5;   // r 0..7
    #pragma unroll
    for (int i = 0; i < 4; ++i)
        t[r + 8 * i][c] = W[(size_t)(k0 + r + 8 * i) * N + n0 + c];
    __syncthreads();
    #pragma unroll
    for (int i = 0; i < 4; ++i)
        WT[(size_t)(rbase + n0 + r + 8 * i) * DIMC + k0 + c] = f2bf(t[c][r + 8 * i]);
}

// ------- fused q/kv GEMM: x[2048,512]f32 (cvt in-reg) @ WT[1536,512]^T -----
// cols 0..511 -> qb bf16 (+bq); cols 512..1535 -> kvb bf16 (+bkv).
__global__ __launch_bounds__(256) void gemm_qkv_k(
    const float* __restrict__ x, const short* __restrict__ WT,
    const float* __restrict__ bq, const float* __restrict__ bkv,
    short* __restrict__ qb, short* __restrict__ kvb)
{
    const int tid = threadIdx.x, w = tid >> 6, lane = tid & 63;
    const int lr = lane & 15, lg = lane >> 4;
    const int m0 = blockIdx.y * 64 + w * 16;
    const int n0 = blockIdx.x * 64;

    const float* Arow = x  + (size_t)(m0 + lr) * DIMC + lg * 8;
    const short* Brow = WT + (size_t)(n0 + lr) * DIMC + lg * 8;

    auto loadA = [&](int k0) -> bf16x8_t {
        const float4 f0 = *reinterpret_cast<const float4*>(Arow + k0);
        const float4 f1 = *reinterpret_cast<const float4*>(Arow + k0 + 4);
        bf16x8_t t;
        t[0]=f2bf(f0.x); t[1]=f2bf(f0.y); t[2]=f2bf(f0.z); t[3]=f2bf(f0.w);
        t[4]=f2bf(f1.x); t[5]=f2bf(f1.y); t[6]=f2bf(f1.z); t[7]=f2bf(f1.w);
        return t;
    };

    f32x4_t acc[4];
    #pragma unroll
    for (int nt = 0; nt < 4; ++nt) acc[nt] = f32x4_t{0.f,0.f,0.f,0.f};

    bf16x8_t a0 = loadA(0);
    bf16x8_t b0[4];
    #pragma unroll
    for (int nt = 0; nt < 4; ++nt)
        b0[nt] = *reinterpret_cast<const bf16x8_t*>(Brow + nt * 16 * DIMC);

    #pragma unroll
    for (int k0 = 0; k0 < 480; k0 += 32) {
        bf16x8_t a1 = loadA(k0 + 32);
        bf16x8_t b1[4];
        #pragma unroll
        for (int nt = 0; nt < 4; ++nt)
            b1[nt] = *reinterpret_cast<const bf16x8_t*>(Brow + nt*16*DIMC + k0 + 32);
        #pragma unroll
        for (int nt = 0; nt < 4; ++nt)
            acc[nt] = __builtin_amdgcn_mfma_f32_16x16x32_bf16(a0, b0[nt], acc[nt], 0,0,0);
        a0 = a1;
        #pragma unroll
        for (int nt = 0; nt < 4; ++nt) b0[nt] = b1[nt];
    }
    #pragma unroll
    for (int nt = 0; nt < 4; ++nt)
        acc[nt] = __builtin_amdgcn_mfma_f32_16x16x32_bf16(a0, b0[nt], acc[nt], 0,0,0);

    if (n0 < 512) {
        #pragma unroll
        for (int nt = 0; nt < 4; ++nt) {
            const int col = n0 + nt * 16 + lr;
            const float bv = bq[col];
            #pragma unroll
            for (int j = 0; j < 4; ++j)
                qb[(size_t)(m0 + lg*4 + j) * DIMC + col] = f2bf(acc[nt][j] + bv);
        }
    } else {
        #pragma unroll
        for (int nt = 0; nt < 4; ++nt) {
            const int col = n0 - 512 + nt * 16 + lr;
            const float bv = bkv[col];
            #pragma unroll
            for (int j = 0; j < 4; ++j)
                kvb[(size_t)(m0 + lg*4 + j) * 1024 + col] = f2bf(acc[nt][j] + bv);
        }
    }
}

// ------- out GEMM: 8 waves, wave 16x32, register-pipelined -----------------
__global__ __launch_bounds__(512) void gemm_out_k(
    const short* __restrict__ A, const short* __restrict__ WT,
    const float* __restrict__ bo, float* __restrict__ C)
{
    const int tid = threadIdx.x, w = tid >> 6, lane = tid & 63;
    const int lr = lane & 15, lg = lane >> 4;
    const int wm = w >> 1, wn = w & 1;
    const int m0 = blockIdx.y * 64 + wm * 16;
    const int n0 = blockIdx.x * 64 + wn * 32;
    const short* Arow = A  + (size_t)(m0 + lr) * DIMC + lg * 8;
    const short* Brow = WT + (size_t)(n0 + lr) * DIMC + lg * 8;
    f32x4_t acc[2];
    acc[0] = f32x4_t{0.f,0.f,0.f,0.f};
    acc[1] = f32x4_t{0.f,0.f,0.f,0.f};
    bf16x8_t a0 = *reinterpret_cast<const bf16x8_t*>(Arow);
    bf16x8_t b0[2];
    b0[0] = *reinterpret_cast<const bf16x8_t*>(Brow);
    b0[1] = *reinterpret_cast<const bf16x8_t*>(Brow + 16 * DIMC);
    #pragma unroll
    for (int k0 = 0; k0 < 480; k0 += 32) {
        bf16x8_t a1 = *reinterpret_cast<const bf16x8_t*>(Arow + k0 + 32);
        bf16x8_t b1[2];
        b1[0] = *reinterpret_cast<const bf16x8_t*>(Brow + k0 + 32);
        b1[1] = *reinterpret_cast<const bf16x8_t*>(Brow + 16 * DIMC + k0 + 32);
        acc[0] = __builtin_amdgcn_mfma_f32_16x16x32_bf16(a0, b0[0], acc[0], 0,0,0);
        acc[1] = __builtin_amdgcn_mfma_f32_16x16x32_bf16(a0, b0[1], acc[1], 0,0,0);
        a0 = a1; b0[0] = b1[0]; b0[1] = b1[1];
    }
    acc[0] = __builtin_amdgcn_mfma_f32_16x16x32_bf16(a0, b0[0], acc[0], 0,0,0);
    acc[1] = __builtin_amdgcn_mfma_f32_16x16x32_bf16(a0, b0[1], acc[1], 0,0,0);
    #pragma unroll
    for (int nt = 0; nt < 2; ++nt) {
        const int col = n0 + nt * 16 + lr;
        const float bv = bo[col];
        #pragma unroll
        for (int j = 0; j < 4; ++j)
            C[(size_t)(m0 + lg * 4 + j) * DIMC + col] = acc[nt][j] + bv;
    }
}

// ------- depthwise 3x3 s2 SAME, bf16 in -> K [b][2048][64], V^T [b][64][2048]
__global__ __launch_bounds__(256) void dwconv_k(
    const short* __restrict__ kvb, const float* __restrict__ kern,
    const float* __restrict__ dbias, short* __restrict__ Kbf,
    short* __restrict__ Vt)
{
    int idx = blockIdx.x * 256 + threadIdx.x;
    const int c  = idx & 1023;
    const int ow = (idx >> 10) & 15;
    const int oh = (idx >> 14) & 15;
    const int b  = idx >> 18;
    float acc = dbias[c];
    #pragma unroll
    for (int kh = 0; kh < 3; ++kh) {
        int ih = oh * 2 + kh;
        if (ih >= Hh) continue;
        #pragma unroll
        for (int kw = 0; kw < 3; ++kw) {
            int iw = ow * 2 + kw;
            if (iw >= Ww) continue;
            acc += bf2f(kvb[(((size_t)b * Hh + ih) * Ww + iw) * 1024 + c])
                 * kern[(kh * 3 + kw) * 1024 + c];
        }
    }
    const int s = oh * KVW + ow;
    if (c < 512) {
        int d = c & 63, ck = c >> 6;
        Kbf[((size_t)b * Mkv + s * 8 + ck) * HD + d] = f2bf(acc);
    } else {
        int c2 = c - 512;
        int d = c2 & 63, ck = c2 >> 6;
        Vt[((size_t)b * HD + d) * Mkv + s * 8 + ck] = f2bf(acc);
    }
}

// ---------------- flash attention, split-m (NC=8), fixed m=0 ---------------
__global__ __launch_bounds__(128) void attn_mfma_k(
    const short* __restrict__ qb, const short* __restrict__ K,
    const short* __restrict__ Vt, short* __restrict__ po,
    float* __restrict__ pl)
{
    __shared__ __align__(16) char smem[20480];
    char* Kl = smem;
    char* Vl = smem + 8192;
    const int tid  = threadIdx.x;
    const int w    = tid >> 6;
    const int lane = tid & 63;
    char* Pl = smem + 16384 + w * 2048;
    const int bid = blockIdx.x;           // 512
    const int chunk = blockIdx.y;         // 0..NC-1
    const int qt  = bid & 31;
    const int n   = (bid >> 5) & 7;
    const int b   = bid >> 8;
    const int q0  = qt * QTILE + w * 16;
    const int lr = lane & 15;
    const int lg = lane >> 4;

    // Q fragments, pre-scaled by SL2E
    bf16x8_t qf[2];
    {
        const short* qrow = qb + ((size_t)(b * Lq) + q0 + lr) * DIMC + n * HD + lg * 8;
        #pragma unroll
        for (int ks = 0; ks < 2; ++ks) {
            bf16x8_t t = *reinterpret_cast<const bf16x8_t*>(qrow + ks * 32);
            #pragma unroll
            for (int j = 0; j < 8; ++j) t[j] = f2bf(bf2f(t[j]) * SL2E);
            qf[ks] = t;
        }
    }

    f32x4_t o[4];
    #pragma unroll
    for (int dt = 0; dt < 4; ++dt) o[dt] = f32x4_t{0.f,0.f,0.f,0.f};
    float lacc[4] = {0.f,0.f,0.f,0.f};

    const short* Kb = K  + (size_t)b * Mkv * HD;
    const short* Vb = Vt + (size_t)b * HD * Mkv;
    const int mbase = chunk * (Mkv / NC);

    const int Lr8 = lane >> 3;
    const int jj  = lane & 7;
    bf16x8_t kreg[4], vreg[4];
    auto load_tile = [&](int mt) {
        #pragma unroll
        for (int c = 0; c < 4; ++c) {
            const int row = c * 16 + w * 8 + Lr8;
            kreg[c] = *reinterpret_cast<const bf16x8_t*>(
                Kb + (size_t)(mt + row) * HD + jj * 8);
            vreg[c] = *reinterpret_cast<const bf16x8_t*>(
                Vb + (size_t)row * Mkv + mt + jj * 8);
        }
    };
    auto write_tile = [&]() {
        #pragma unroll
        for (int c = 0; c < 4; ++c) {
            const int row = c * 16 + w * 8 + Lr8;
            const int off = row * 128 + ((jj * 16) ^ ((row & 7) << 4));
            *reinterpret_cast<bf16x8_t*>(Kl + off) = kreg[c];
            *reinterpret_cast<bf16x8_t*>(Vl + off) = vreg[c];
        }
    };

    load_tile(mbase);
    for (int it = 0; it < ITERS; ++it) {
        write_tile();
        __syncthreads();
        if (it < ITERS - 1) load_tile(mbase + (it + 1) * MTILE);

        f32x4_t s[4];
        __builtin_amdgcn_s_setprio(1);
        #pragma unroll
        for (int nt = 0; nt < 4; ++nt) {
            const int ml = nt * 16 + lr;
            f32x4_t acc = f32x4_t{0.f,0.f,0.f,0.f};
            bf16x8_t k0 = *reinterpret_cast<bf16x8_t*>(
                Kl + ml * 128 + ((lg * 16)      ^ ((ml & 7) << 4)));
            bf16x8_t k1 = *reinterpret_cast<bf16x8_t*>(
                Kl + ml * 128 + ((64 + lg * 16) ^ ((ml & 7) << 4)));
            acc = __builtin_amdgcn_mfma_f32_16x16x32_bf16(qf[0], k0, acc, 0,0,0);
            acc = __builtin_amdgcn_mfma_f32_16x16x32_bf16(qf[1], k1, acc, 0,0,0);
            s[nt] = acc;
        }
        __builtin_amdgcn_s_setprio(0);
        #pragma unroll
        for (int nt = 0; nt < 4; ++nt)
            #pragma unroll
            for (int r = 0; r < 4; ++r) {
                float p = exp2f(s[nt][r]);
                s[nt][r] = p;
                lacc[r] += p;
            }

        #pragma unroll
        for (int nt = 0; nt < 4; ++nt)
            #pragma unroll
            for (int r = 0; r < 4; ++r) {
                const int qL = lg * 4 + r;
                const int mL = nt * 16 + lr;
                *reinterpret_cast<short*>(
                    Pl + qL * 128 + ((mL * 2) ^ ((qL & 7) << 4))) = f2bf(s[nt][r]);
            }

        bf16x8_t pf[2];
        #pragma unroll
        for (int ks2 = 0; ks2 < 2; ++ks2)
            pf[ks2] = *reinterpret_cast<bf16x8_t*>(
                Pl + lr * 128 + ((ks2 * 64 + lg * 16) ^ ((lr & 7) << 4)));
        __builtin_amdgcn_s_setprio(1);
        #pragma unroll
        for (int dt = 0; dt < 4; ++dt) {
            const int dL = dt * 16 + lr;
            #pragma unroll
            for (int ks2 = 0; ks2 < 2; ++ks2) {
                bf16x8_t vb = *reinterpret_cast<bf16x8_t*>(
                    Vl + dL * 128 + ((ks2 * 64 + lg * 16) ^ ((dL & 7) << 4)));
                o[dt] = __builtin_amdgcn_mfma_f32_16x16x32_bf16(pf[ks2], vb, o[dt], 0,0,0);
            }
        }
        __builtin_amdgcn_s_setprio(0);
        __syncthreads();
    }

    #pragma unroll
    for (int r = 0; r < 4; ++r) {
        float l = lacc[r];
        l += __shfl_xor(l, 1);
        l += __shfl_xor(l, 2);
        l += __shfl_xor(l, 4);
        l += __shfl_xor(l, 8);
        const float inv = 1.0f / l;
        const int grow = ((b * NHEADS + n) << 10) + q0 + lg * 4 + r;
        #pragma unroll
        for (int dt = 0; dt < 4; ++dt)
            po[((size_t)chunk * NROWS + grow) * HD + dt * 16 + lr] = f2bf(o[dt][r] * inv);
        if (lr == 0) pl[chunk * NROWS + grow] = l;
    }
}

// ---------------- combine partials (x8 vectorized, NC=8) -------------------
__global__ __launch_bounds__(256) void attn_combine_k(
    const short* __restrict__ po, const float* __restrict__ pl,
    short* __restrict__ aob)
{
    const int idx = blockIdx.x * 256 + threadIdx.x;   // NROWS*8 = 131072
    const int grow = idx >> 3, dc = idx & 7;
    float l[NC], lsum = 0.f;
    #pragma unroll
    for (int c = 0; c < NC; ++c) { l[c] = pl[c * NROWS + grow]; lsum += l[c]; }
    float num[8] = {};
    #pragma unroll
    for (int c = 0; c < NC; ++c) {
        bf16x8_t v = *reinterpret_cast<const bf16x8_t*>(
            po + ((size_t)c * NROWS + grow) * HD + dc * 8);
        #pragma unroll
        for (int j = 0; j < 8; ++j) num[j] += l[c] * bf2f(v[j]);
    }
    const float inv = 1.0f / lsum;
    bf16x8_t r;
    #pragma unroll
    for (int j = 0; j < 8; ++j) r[j] = f2bf(num[j] * inv);
    const int b = grow >> 13, n = (grow >> 10) & 7, qrow = grow & 1023;
    *reinterpret_cast<bf16x8_t*>(
        aob + ((size_t)((b << 10) + qrow)) * DIMC + (n << 6) + dc * 8) = r;
}

extern "C" void kernel_launch(void* const* d_in, const int* in_sizes, int n_in,
                              void* d_out, int out_size, void* d_ws, size_t ws_size,
                              hipStream_t stream)
{
    const float* x    = (const float*)d_in[0];
    const float* wq   = (const float*)d_in[1];
    const float* bq   = (const float*)d_in[2];
    const float* wkv  = (const float*)d_in[3];
    const float* bkv  = (const float*)d_in[4];
    const float* dwk  = (const float*)d_in[5];
    const float* dwb  = (const float*)d_in[6];
    const float* wo   = (const float*)d_in[7];
    const float* bo   = (const float*)d_in[8];
    float* out = (float*)d_out;

    // scratch: po/pl (17.3 MB) written in attn; kvb (4 MB) overlays po
    // (kvb dead after dwconv, before attn writes po). persistent after pl.
    short* po    = (short*)d_ws;                          // 8*16384*64 bf16
    float* pl    = (float*)(po + (size_t)NC * NROWS * HD);// 8*16384 f32
    short* wqkvT = (short*)(pl + (size_t)NC * NROWS);     // 1536*512
    short* woT   = wqkvT + (size_t)3 * DIMC * DIMC;       // 512*512
    short* qb    = woT   + (size_t)DIMC * DIMC;           // 2048*512
    short* Kbf   = qb    + (size_t)BHW * DIMC;            // 2*2048*64
    short* Vt    = Kbf   + (size_t)Bb * Mkv * HD;         // 2*64*2048
    short* aob   = Vt    + (size_t)Bb * HD * Mkv;         // 2048*512
    short* kvb   = (short*)d_ws;                          // 2048*1024 bf16 (overlay)

    prep_k<<<dim3(32, 16, 3), 256, 0, stream>>>(wq, wkv, wo, wqkvT, woT);

    gemm_qkv_k<<<dim3(24, 32), 256, 0, stream>>>(x, wqkvT, bq, bkv, qb, kvb);

    dwconv_k<<<(Bb * KVH * KVW * 1024) / 256, 256, 0, stream>>>(
        kvb, dwk, dwb, Kbf, Vt);

    attn_mfma_k<<<dim3(Bb * NHEADS * (Lq / QTILE), NC), 128, 0, stream>>>(
        qb, Kbf, Vt, po, pl);
    attn_combine_k<<<NROWS * 8 / 256, 256, 0, stream>>>(po, pl, aob);

    gemm_out_k<<<dim3(8, 32), 512, 0, stream>>>(aob, woT, bo, out);
}

// Round 11
// 71.117 us; speedup vs baseline: 5.5937x; 1.3256x over previous
//
#include <hip/hip_runtime.h>
#include <hip/hip_bf16.h>

#define DIMC   512
#define NHEADS 8
#define HD     64
#define Bb     2
#define Hh     32
#define Ww     32
#define Lq     1024          // H*W
#define BHW    2048          // B*H*W
#define KVH    16
#define KVW    16
#define Mkv    2048          // KVH*KVW*NHEADS
#define SL2E   0.18033688011112042f   // (1/8) * log2(e)
#define NC     4             // attention m-chunks (split-K)
#define NROWS  (Bb * NHEADS * Lq)     // 16384 partial rows

typedef short bf16x8_t __attribute__((ext_vector_type(8)));
typedef float f32x4_t  __attribute__((ext_vector_type(4)));

__device__ __forceinline__ short f2bf(float f) {
    __hip_bfloat16 h = __float2bfloat16(f);
    return *reinterpret_cast<short*>(&h);
}
__device__ __forceinline__ float bf2f(short s) {
    unsigned u = ((unsigned)(unsigned short)s) << 16;
    return *reinterpret_cast<float*>(&u);
}

#define QTILE 32
#define MTILE 64
#define ITERS (Mkv / NC / MTILE)   // 8

// ------- prep: cast x -> bf16 (z=0) + transpose wq/wkv/wo (z=1..3) ---------
__global__ __launch_bounds__(256) void prep_k(
    const float* __restrict__ x, short* __restrict__ xb,
    const float* __restrict__ wq, const float* __restrict__ wkv,
    const float* __restrict__ wo, short* __restrict__ wqkvT,
    short* __restrict__ woT)
{
    const int z = blockIdx.z;
    if (z == 0) {
        const int i = (blockIdx.y * 32 + blockIdx.x) * 256 + threadIdx.x;
        const float4 f0 = reinterpret_cast<const float4*>(x)[i * 2 + 0];
        const float4 f1 = reinterpret_cast<const float4*>(x)[i * 2 + 1];
        bf16x8_t t;
        t[0]=f2bf(f0.x); t[1]=f2bf(f0.y); t[2]=f2bf(f0.z); t[3]=f2bf(f0.w);
        t[4]=f2bf(f1.x); t[5]=f2bf(f1.y); t[6]=f2bf(f1.z); t[7]=f2bf(f1.w);
        reinterpret_cast<bf16x8_t*>(xb)[i] = t;
        return;
    }
    const float* W; short* WT; int N, rbase;
    if (z == 1)      { W = wq;  WT = wqkvT; N = DIMC;     rbase = 0;   }
    else if (z == 2) { W = wkv; WT = wqkvT; N = 2 * DIMC; rbase = 512; }
    else             { W = wo;  WT = woT;   N = DIMC;     rbase = 0;   }
    const int n0 = blockIdx.x * 32, k0 = blockIdx.y * 32;
    if (n0 >= N) return;
    __shared__ float t[32][33];
    const int c = threadIdx.x & 31, r = threadIdx.x >> 5;   // r 0..7
    #pragma unroll
    for (int i = 0; i < 4; ++i)
        t[r + 8 * i][c] = W[(size_t)(k0 + r + 8 * i) * N + n0 + c];
    __syncthreads();
    #pragma unroll
    for (int i = 0; i < 4; ++i)
        WT[(size_t)(rbase + n0 + r + 8 * i) * DIMC + k0 + c] = f2bf(t[c][r + 8 * i]);
}

// ------- LDS-tiled q/kv GEMM: xb[2048,512] @ wqkvT[1536,512]^T -------------
// block 64x64, 4 waves (2x2 of 32x32), BK=64, double-buffered LDS (swizzled).
// One barrier per K-iter (double-buffer makes the 2nd unnecessary).
__global__ __launch_bounds__(256) void gemm_qkv_k(
    const short* __restrict__ A, const short* __restrict__ WT,
    const float* __restrict__ bq, const float* __restrict__ bkv,
    short* __restrict__ qb, short* __restrict__ kvb)
{
    __shared__ __align__(16) char smem[32768];   // [buf][A 8K | B 8K]
    const int tid = threadIdx.x, w = tid >> 6, lane = tid & 63;
    const int lr = lane & 15, lg = lane >> 4;
    const int wm = w >> 1, wn = w & 1;
    const int m0 = blockIdx.y * 64;
    const int n0 = blockIdx.x * 64;

    // staging: thread -> (row sr 0..63, 16-elem group sc 0..3)
    const int sr = tid >> 2, sc = tid & 3;
    const short* Asrc = A  + (size_t)(m0 + sr) * DIMC + sc * 16;
    const short* Bsrc = WT + (size_t)(n0 + sr) * DIMC + sc * 16;
    bf16x8_t ar[2], br[2];
    auto load_stage = [&](int kc) {
        ar[0] = *reinterpret_cast<const bf16x8_t*>(Asrc + kc);
        ar[1] = *reinterpret_cast<const bf16x8_t*>(Asrc + kc + 8);
        br[0] = *reinterpret_cast<const bf16x8_t*>(Bsrc + kc);
        br[1] = *reinterpret_cast<const bf16x8_t*>(Bsrc + kc + 8);
    };
    const int rowb = sr * 128;
    const int swzw = (sr & 7) << 4;
    auto write_stage = [&](int bb) {
        char* S = smem + bb * 16384;
        *reinterpret_cast<bf16x8_t*>(S +        rowb + ((sc*32     ) ^ swzw)) = ar[0];
        *reinterpret_cast<bf16x8_t*>(S +        rowb + ((sc*32 + 16) ^ swzw)) = ar[1];
        *reinterpret_cast<bf16x8_t*>(S + 8192 + rowb + ((sc*32     ) ^ swzw)) = br[0];
        *reinterpret_cast<bf16x8_t*>(S + 8192 + rowb + ((sc*32 + 16) ^ swzw)) = br[1];
    };

    f32x4_t acc[2][2];
    #pragma unroll
    for (int i = 0; i < 2; ++i)
        #pragma unroll
        for (int j = 0; j < 2; ++j) acc[i][j] = f32x4_t{0.f,0.f,0.f,0.f};

    load_stage(0);
    write_stage(0);
    int cur = 0;

    for (int it = 0; it < 8; ++it) {
        __syncthreads();                       // buf[cur] fully written
        if (it < 7) load_stage((it + 1) * 64); // prefetch under compute

        char* S = smem + cur * 16384;
        bf16x8_t af[2][2], bf[2][2];
        #pragma unroll
        for (int s = 0; s < 2; ++s) {
            const int arow = wm * 32 + s * 16 + lr;
            const int brow = wn * 32 + s * 16 + lr;
            #pragma unroll
            for (int h = 0; h < 2; ++h) {
                af[s][h] = *reinterpret_cast<bf16x8_t*>(
                    S +        arow * 128 + ((h*64 + lg*16) ^ ((arow & 7) << 4)));
                bf[s][h] = *reinterpret_cast<bf16x8_t*>(
                    S + 8192 + brow * 128 + ((h*64 + lg*16) ^ ((brow & 7) << 4)));
            }
        }
        __builtin_amdgcn_s_setprio(1);
        #pragma unroll
        for (int ms = 0; ms < 2; ++ms)
            #pragma unroll
            for (int ns = 0; ns < 2; ++ns)
                #pragma unroll
                for (int h = 0; h < 2; ++h)
                    acc[ms][ns] = __builtin_amdgcn_mfma_f32_16x16x32_bf16(
                        af[ms][h], bf[ns][h], acc[ms][ns], 0, 0, 0);
        __builtin_amdgcn_s_setprio(0);

        if (it < 7) write_stage(cur ^ 1);      // other buffer: safe post-barrier
        cur ^= 1;
    }

    // epilogue
    if (n0 < 512) {
        #pragma unroll
        for (int ns = 0; ns < 2; ++ns) {
            const int col = n0 + wn * 32 + ns * 16 + lr;
            const float bv = bq[col];
            #pragma unroll
            for (int ms = 0; ms < 2; ++ms) {
                const int row = m0 + wm * 32 + ms * 16 + lg * 4;
                #pragma unroll
                for (int j = 0; j < 4; ++j)
                    qb[(size_t)(row + j) * DIMC + col] = f2bf(acc[ms][ns][j] + bv);
            }
        }
    } else {
        #pragma unroll
        for (int ns = 0; ns < 2; ++ns) {
            const int col = n0 - 512 + wn * 32 + ns * 16 + lr;
            const float bv = bkv[col];
            #pragma unroll
            for (int ms = 0; ms < 2; ++ms) {
                const int row = m0 + wm * 32 + ms * 16 + lg * 4;
                #pragma unroll
                for (int j = 0; j < 4; ++j)
                    kvb[(size_t)(row + j) * 1024 + col] = f2bf(acc[ms][ns][j] + bv);
            }
        }
    }
}

// ------- out GEMM: 8 waves, wave 16x32, register-pipelined (R7 proven) -----
__global__ __launch_bounds__(512) void gemm_out_k(
    const short* __restrict__ A, const short* __restrict__ WT,
    const float* __restrict__ bo, float* __restrict__ C)
{
    const int tid = threadIdx.x, w = tid >> 6, lane = tid & 63;
    const int lr = lane & 15, lg = lane >> 4;
    const int wm = w >> 1, wn = w & 1;
    const int m0 = blockIdx.y * 64 + wm * 16;
    const int n0 = blockIdx.x * 64 + wn * 32;
    const short* Arow = A  + (size_t)(m0 + lr) * DIMC + lg * 8;
    const short* Brow = WT + (size_t)(n0 + lr) * DIMC + lg * 8;
    f32x4_t acc[2];
    acc[0] = f32x4_t{0.f,0.f,0.f,0.f};
    acc[1] = f32x4_t{0.f,0.f,0.f,0.f};
    bf16x8_t a0 = *reinterpret_cast<const bf16x8_t*>(Arow);
    bf16x8_t b0[2];
    b0[0] = *reinterpret_cast<const bf16x8_t*>(Brow);
    b0[1] = *reinterpret_cast<const bf16x8_t*>(Brow + 16 * DIMC);
    #pragma unroll
    for (int k0 = 0; k0 < 480; k0 += 32) {
        bf16x8_t a1 = *reinterpret_cast<const bf16x8_t*>(Arow + k0 + 32);
        bf16x8_t b1[2];
        b1[0] = *reinterpret_cast<const bf16x8_t*>(Brow + k0 + 32);
        b1[1] = *reinterpret_cast<const bf16x8_t*>(Brow + 16 * DIMC + k0 + 32);
        acc[0] = __builtin_amdgcn_mfma_f32_16x16x32_bf16(a0, b0[0], acc[0], 0,0,0);
        acc[1] = __builtin_amdgcn_mfma_f32_16x16x32_bf16(a0, b0[1], acc[1], 0,0,0);
        a0 = a1; b0[0] = b1[0]; b0[1] = b1[1];
    }
    acc[0] = __builtin_amdgcn_mfma_f32_16x16x32_bf16(a0, b0[0], acc[0], 0,0,0);
    acc[1] = __builtin_amdgcn_mfma_f32_16x16x32_bf16(a0, b0[1], acc[1], 0,0,0);
    #pragma unroll
    for (int nt = 0; nt < 2; ++nt) {
        const int col = n0 + nt * 16 + lr;
        const float bv = bo[col];
        #pragma unroll
        for (int j = 0; j < 4; ++j)
            C[(size_t)(m0 + lg * 4 + j) * DIMC + col] = acc[nt][j] + bv;
    }
}

// ------- depthwise 3x3 s2 SAME, bf16 in -> K [b][2048][64], V^T [b][64][2048]
__global__ __launch_bounds__(256) void dwconv_k(
    const short* __restrict__ kvb, const float* __restrict__ kern,
    const float* __restrict__ dbias, short* __restrict__ Kbf,
    short* __restrict__ Vt)
{
    int idx = blockIdx.x * 256 + threadIdx.x;
    const int c  = idx & 1023;
    const int ow = (idx >> 10) & 15;
    const int oh = (idx >> 14) & 15;
    const int b  = idx >> 18;
    float acc = dbias[c];
    #pragma unroll
    for (int kh = 0; kh < 3; ++kh) {
        int ih = oh * 2 + kh;
        if (ih >= Hh) continue;
        #pragma unroll
        for (int kw = 0; kw < 3; ++kw) {
            int iw = ow * 2 + kw;
            if (iw >= Ww) continue;
            acc += bf2f(kvb[(((size_t)b * Hh + ih) * Ww + iw) * 1024 + c])
                 * kern[(kh * 3 + kw) * 1024 + c];
        }
    }
    const int s = oh * KVW + ow;
    if (c < 512) {
        int d = c & 63, ck = c >> 6;
        Kbf[((size_t)b * Mkv + s * 8 + ck) * HD + d] = f2bf(acc);
    } else {
        int c2 = c - 512;
        int d = c2 & 63, ck = c2 >> 6;
        Vt[((size_t)b * HD + d) * Mkv + s * 8 + ck] = f2bf(acc);
    }
}

// ---------------- flash attention, split-m (NC=4), fixed m=0 ---------------
__global__ __launch_bounds__(128) void attn_mfma_k(
    const short* __restrict__ qb, const short* __restrict__ K,
    const short* __restrict__ Vt, short* __restrict__ po,
    float* __restrict__ pl)
{
    __shared__ __align__(16) char smem[20480];
    char* Kl = smem;
    char* Vl = smem + 8192;
    const int tid  = threadIdx.x;
    const int w    = tid >> 6;
    const int lane = tid & 63;
    char* Pl = smem + 16384 + w * 2048;
    const int bid = blockIdx.x;           // 512
    const int chunk = blockIdx.y;         // 0..NC-1
    const int qt  = bid & 31;
    const int n   = (bid >> 5) & 7;
    const int b   = bid >> 8;
    const int q0  = qt * QTILE + w * 16;
    const int lr = lane & 15;
    const int lg = lane >> 4;

    bf16x8_t qf[2];
    {
        const short* qrow = qb + ((size_t)(b * Lq) + q0 + lr) * DIMC + n * HD + lg * 8;
        #pragma unroll
        for (int ks = 0; ks < 2; ++ks) {
            bf16x8_t t = *reinterpret_cast<const bf16x8_t*>(qrow + ks * 32);
            #pragma unroll
            for (int j = 0; j < 8; ++j) t[j] = f2bf(bf2f(t[j]) * SL2E);
            qf[ks] = t;
        }
    }

    f32x4_t o[4];
    #pragma unroll
    for (int dt = 0; dt < 4; ++dt) o[dt] = f32x4_t{0.f,0.f,0.f,0.f};
    float lacc[4] = {0.f,0.f,0.f,0.f};

    const short* Kb = K  + (size_t)b * Mkv * HD;
    const short* Vb = Vt + (size_t)b * HD * Mkv;
    const int mbase = chunk * (Mkv / NC);

    const int Lr8 = lane >> 3;
    const int jj  = lane & 7;
    bf16x8_t kreg[4], vreg[4];
    auto load_tile = [&](int mt) {
        #pragma unroll
        for (int c = 0; c < 4; ++c) {
            const int row = c * 16 + w * 8 + Lr8;
            kreg[c] = *reinterpret_cast<const bf16x8_t*>(
                Kb + (size_t)(mt + row) * HD + jj * 8);
            vreg[c] = *reinterpret_cast<const bf16x8_t*>(
                Vb + (size_t)row * Mkv + mt + jj * 8);
        }
    };
    auto write_tile = [&]() {
        #pragma unroll
        for (int c = 0; c < 4; ++c) {
            const int row = c * 16 + w * 8 + Lr8;
            const int off = row * 128 + ((jj * 16) ^ ((row & 7) << 4));
            *reinterpret_cast<bf16x8_t*>(Kl + off) = kreg[c];
            *reinterpret_cast<bf16x8_t*>(Vl + off) = vreg[c];
        }
    };

    load_tile(mbase);
    for (int it = 0; it < ITERS; ++it) {
        write_tile();
        __syncthreads();
        if (it < ITERS - 1) load_tile(mbase + (it + 1) * MTILE);

        f32x4_t s[4];
        __builtin_amdgcn_s_setprio(1);
        #pragma unroll
        for (int nt = 0; nt < 4; ++nt) {
            const int ml = nt * 16 + lr;
            f32x4_t acc = f32x4_t{0.f,0.f,0.f,0.f};
            bf16x8_t k0 = *reinterpret_cast<bf16x8_t*>(
                Kl + ml * 128 + ((lg * 16)      ^ ((ml & 7) << 4)));
            bf16x8_t k1 = *reinterpret_cast<bf16x8_t*>(
                Kl + ml * 128 + ((64 + lg * 16) ^ ((ml & 7) << 4)));
            acc = __builtin_amdgcn_mfma_f32_16x16x32_bf16(qf[0], k0, acc, 0,0,0);
            acc = __builtin_amdgcn_mfma_f32_16x16x32_bf16(qf[1], k1, acc, 0,0,0);
            s[nt] = acc;
        }
        __builtin_amdgcn_s_setprio(0);
        #pragma unroll
        for (int nt = 0; nt < 4; ++nt)
            #pragma unroll
            for (int r = 0; r < 4; ++r) {
                float p = exp2f(s[nt][r]);
                s[nt][r] = p;
                lacc[r] += p;
            }

        #pragma unroll
        for (int nt = 0; nt < 4; ++nt)
            #pragma unroll
            for (int r = 0; r < 4; ++r) {
                const int qL = lg * 4 + r;
                const int mL = nt * 16 + lr;
                *reinterpret_cast<short*>(
                    Pl + qL * 128 + ((mL * 2) ^ ((qL & 7) << 4))) = f2bf(s[nt][r]);
            }

        bf16x8_t pf[2];
        #pragma unroll
        for (int ks2 = 0; ks2 < 2; ++ks2)
            pf[ks2] = *reinterpret_cast<bf16x8_t*>(
                Pl + lr * 128 + ((ks2 * 64 + lg * 16) ^ ((lr & 7) << 4)));
        __builtin_amdgcn_s_setprio(1);
        #pragma unroll
        for (int dt = 0; dt < 4; ++dt) {
            const int dL = dt * 16 + lr;
            #pragma unroll
            for (int ks2 = 0; ks2 < 2; ++ks2) {
                bf16x8_t vb = *reinterpret_cast<bf16x8_t*>(
                    Vl + dL * 128 + ((ks2 * 64 + lg * 16) ^ ((dL & 7) << 4)));
                o[dt] = __builtin_amdgcn_mfma_f32_16x16x32_bf16(pf[ks2], vb, o[dt], 0,0,0);
            }
        }
        __builtin_amdgcn_s_setprio(0);
        __syncthreads();
    }

    #pragma unroll
    for (int r = 0; r < 4; ++r) {
        float l = lacc[r];
        l += __shfl_xor(l, 1);
        l += __shfl_xor(l, 2);
        l += __shfl_xor(l, 4);
        l += __shfl_xor(l, 8);
        const float inv = 1.0f / l;
        const int grow = ((b * NHEADS + n) << 10) + q0 + lg * 4 + r;
        #pragma unroll
        for (int dt = 0; dt < 4; ++dt)
            po[((size_t)chunk * NROWS + grow) * HD + dt * 16 + lr] = f2bf(o[dt][r] * inv);
        if (lr == 0) pl[chunk * NROWS + grow] = l;
    }
}

// ---------------- combine partials (x8 vectorized, NC=4) -------------------
__global__ __launch_bounds__(256) void attn_combine_k(
    const short* __restrict__ po, const float* __restrict__ pl,
    short* __restrict__ aob)
{
    const int idx = blockIdx.x * 256 + threadIdx.x;   // NROWS*8 = 131072
    const int grow = idx >> 3, dc = idx & 7;
    float l[NC], lsum = 0.f;
    #pragma unroll
    for (int c = 0; c < NC; ++c) { l[c] = pl[c * NROWS + grow]; lsum += l[c]; }
    float num[8] = {};
    #pragma unroll
    for (int c = 0; c < NC; ++c) {
        bf16x8_t v = *reinterpret_cast<const bf16x8_t*>(
            po + ((size_t)c * NROWS + grow) * HD + dc * 8);
        #pragma unroll
        for (int j = 0; j < 8; ++j) num[j] += l[c] * bf2f(v[j]);
    }
    const float inv = 1.0f / lsum;
    bf16x8_t r;
    #pragma unroll
    for (int j = 0; j < 8; ++j) r[j] = f2bf(num[j] * inv);
    const int b = grow >> 13, n = (grow >> 10) & 7, qrow = grow & 1023;
    *reinterpret_cast<bf16x8_t*>(
        aob + ((size_t)((b << 10) + qrow)) * DIMC + (n << 6) + dc * 8) = r;
}

extern "C" void kernel_launch(void* const* d_in, const int* in_sizes, int n_in,
                              void* d_out, int out_size, void* d_ws, size_t ws_size,
                              hipStream_t stream)
{
    const float* x    = (const float*)d_in[0];
    const float* wq   = (const float*)d_in[1];
    const float* bq   = (const float*)d_in[2];
    const float* wkv  = (const float*)d_in[3];
    const float* bkv  = (const float*)d_in[4];
    const float* dwk  = (const float*)d_in[5];
    const float* dwb  = (const float*)d_in[6];
    const float* wo   = (const float*)d_in[7];
    const float* bo   = (const float*)d_in[8];
    float* out = (float*)d_out;

    // scratch region (first 8.7 MB): po/pl overlay kvb+xb (dead before attn)
    short* po    = (short*)d_ws;                          // 4*16384*64 bf16 (8.4MB)
    float* pl    = (float*)(po + (size_t)NC * NROWS * HD);// 4*16384 f32
    short* kvb   = (short*)d_ws;                          // 2048*1024 bf16 (4MB, overlay)
    short* xb    = kvb + (size_t)BHW * 1024;              // 2048*512 bf16 (2MB, overlay)
    // persistent (after pl)
    short* wqkvT = (short*)(pl + (size_t)NC * NROWS);     // 1536*512
    short* woT   = wqkvT + (size_t)3 * DIMC * DIMC;       // 512*512
    short* qb    = woT   + (size_t)DIMC * DIMC;           // 2048*512
    short* Kbf   = qb    + (size_t)BHW * DIMC;            // 2*2048*64
    short* Vt    = Kbf   + (size_t)Bb * Mkv * HD;         // 2*64*2048
    short* aob   = Vt    + (size_t)Bb * HD * Mkv;         // 2048*512

    prep_k<<<dim3(32, 16, 4), 256, 0, stream>>>(x, xb, wq, wkv, wo, wqkvT, woT);

    gemm_qkv_k<<<dim3(24, 32), 256, 0, stream>>>(xb, wqkvT, bq, bkv, qb, kvb);

    dwconv_k<<<(Bb * KVH * KVW * 1024) / 256, 256, 0, stream>>>(
        kvb, dwk, dwb, Kbf, Vt);

    attn_mfma_k<<<dim3(Bb * NHEADS * (Lq / QTILE), NC), 128, 0, stream>>>(
        qb, Kbf, Vt, po, pl);
    attn_combine_k<<<NROWS * 8 / 256, 256, 0, stream>>>(po, pl, aob);

    gemm_out_k<<<dim3(8, 32), 512, 0, stream>>>(aob, woT, bo, out);
}

// Round 12
// 68.097 us; speedup vs baseline: 5.8417x; 1.0443x over previous
//
#include <hip/hip_runtime.h>
#include <hip/hip_bf16.h>

#define DIMC   512
#define NHEADS 8
#define HD     64
#define Bb     2
#define Hh     32
#define Ww     32
#define Lq     1024          // H*W
#define BHW    2048          // B*H*W
#define KVH    16
#define KVW    16
#define Mkv    2048          // KVH*KVW*NHEADS
#define SL2E   0.18033688011112042f   // (1/8) * log2(e)
#define NC     4             // attention m-chunks (split-K)
#define NROWS  (Bb * NHEADS * Lq)     // 16384 partial rows

typedef short bf16x8_t __attribute__((ext_vector_type(8)));
typedef float f32x4_t  __attribute__((ext_vector_type(4)));

__device__ __forceinline__ short f2bf(float f) {
    __hip_bfloat16 h = __float2bfloat16(f);
    return *reinterpret_cast<short*>(&h);
}
__device__ __forceinline__ float bf2f(short s) {
    unsigned u = ((unsigned)(unsigned short)s) << 16;
    return *reinterpret_cast<float*>(&u);
}

#define QTILE 32
#define MTILE 64
#define ITERS (Mkv / NC / MTILE)   // 8

// ------- prep: cast x -> bf16 (z=0) + transpose wq/wkv/wo (z=1..3) ---------
__global__ __launch_bounds__(256) void prep_k(
    const float* __restrict__ x, short* __restrict__ xb,
    const float* __restrict__ wq, const float* __restrict__ wkv,
    const float* __restrict__ wo, short* __restrict__ wqkvT,
    short* __restrict__ woT)
{
    const int z = blockIdx.z;
    if (z == 0) {
        const int i = (blockIdx.y * 32 + blockIdx.x) * 256 + threadIdx.x;
        const float4 f0 = reinterpret_cast<const float4*>(x)[i * 2 + 0];
        const float4 f1 = reinterpret_cast<const float4*>(x)[i * 2 + 1];
        bf16x8_t t;
        t[0]=f2bf(f0.x); t[1]=f2bf(f0.y); t[2]=f2bf(f0.z); t[3]=f2bf(f0.w);
        t[4]=f2bf(f1.x); t[5]=f2bf(f1.y); t[6]=f2bf(f1.z); t[7]=f2bf(f1.w);
        reinterpret_cast<bf16x8_t*>(xb)[i] = t;
        return;
    }
    const float* W; short* WT; int N, rbase;
    if (z == 1)      { W = wq;  WT = wqkvT; N = DIMC;     rbase = 0;   }
    else if (z == 2) { W = wkv; WT = wqkvT; N = 2 * DIMC; rbase = 512; }
    else             { W = wo;  WT = woT;   N = DIMC;     rbase = 0;   }
    const int n0 = blockIdx.x * 32, k0 = blockIdx.y * 32;
    if (n0 >= N) return;
    __shared__ float t[32][33];
    const int c = threadIdx.x & 31, r = threadIdx.x >> 5;   // r 0..7
    #pragma unroll
    for (int i = 0; i < 4; ++i)
        t[r + 8 * i][c] = W[(size_t)(k0 + r + 8 * i) * N + n0 + c];
    __syncthreads();
    #pragma unroll
    for (int i = 0; i < 4; ++i)
        WT[(size_t)(rbase + n0 + r + 8 * i) * DIMC + k0 + c] = f2bf(t[c][r + 8 * i]);
}

// ------- LDS-tiled q/kv GEMM: xb[2048,512] @ wqkvT[1536,512]^T -------------
// block 64x64, 4 waves (2x2 of 32x32), BK=64, double-buffered LDS (swizzled).
__global__ __launch_bounds__(256) void gemm_qkv_k(
    const short* __restrict__ A, const short* __restrict__ WT,
    const float* __restrict__ bq, const float* __restrict__ bkv,
    short* __restrict__ qb, short* __restrict__ kvb)
{
    __shared__ __align__(16) char smem[32768];   // [buf][A 8K | B 8K]
    const int tid = threadIdx.x, w = tid >> 6, lane = tid & 63;
    const int lr = lane & 15, lg = lane >> 4;
    const int wm = w >> 1, wn = w & 1;
    const int m0 = blockIdx.y * 64;
    const int n0 = blockIdx.x * 64;

    const int sr = tid >> 2, sc = tid & 3;
    const short* Asrc = A  + (size_t)(m0 + sr) * DIMC + sc * 16;
    const short* Bsrc = WT + (size_t)(n0 + sr) * DIMC + sc * 16;
    bf16x8_t ar[2], br[2];
    auto load_stage = [&](int kc) {
        ar[0] = *reinterpret_cast<const bf16x8_t*>(Asrc + kc);
        ar[1] = *reinterpret_cast<const bf16x8_t*>(Asrc + kc + 8);
        br[0] = *reinterpret_cast<const bf16x8_t*>(Bsrc + kc);
        br[1] = *reinterpret_cast<const bf16x8_t*>(Bsrc + kc + 8);
    };
    const int rowb = sr * 128;
    const int swzw = (sr & 7) << 4;
    auto write_stage = [&](int bb) {
        char* S = smem + bb * 16384;
        *reinterpret_cast<bf16x8_t*>(S +        rowb + ((sc*32     ) ^ swzw)) = ar[0];
        *reinterpret_cast<bf16x8_t*>(S +        rowb + ((sc*32 + 16) ^ swzw)) = ar[1];
        *reinterpret_cast<bf16x8_t*>(S + 8192 + rowb + ((sc*32     ) ^ swzw)) = br[0];
        *reinterpret_cast<bf16x8_t*>(S + 8192 + rowb + ((sc*32 + 16) ^ swzw)) = br[1];
    };

    f32x4_t acc[2][2];
    #pragma unroll
    for (int i = 0; i < 2; ++i)
        #pragma unroll
        for (int j = 0; j < 2; ++j) acc[i][j] = f32x4_t{0.f,0.f,0.f,0.f};

    load_stage(0);
    write_stage(0);
    int cur = 0;

    for (int it = 0; it < 8; ++it) {
        __syncthreads();
        if (it < 7) load_stage((it + 1) * 64);

        char* S = smem + cur * 16384;
        bf16x8_t af[2][2], bf[2][2];
        #pragma unroll
        for (int s = 0; s < 2; ++s) {
            const int arow = wm * 32 + s * 16 + lr;
            const int brow = wn * 32 + s * 16 + lr;
            #pragma unroll
            for (int h = 0; h < 2; ++h) {
                af[s][h] = *reinterpret_cast<bf16x8_t*>(
                    S +        arow * 128 + ((h*64 + lg*16) ^ ((arow & 7) << 4)));
                bf[s][h] = *reinterpret_cast<bf16x8_t*>(
                    S + 8192 + brow * 128 + ((h*64 + lg*16) ^ ((brow & 7) << 4)));
            }
        }
        __builtin_amdgcn_s_setprio(1);
        #pragma unroll
        for (int ms = 0; ms < 2; ++ms)
            #pragma unroll
            for (int ns = 0; ns < 2; ++ns)
                #pragma unroll
                for (int h = 0; h < 2; ++h)
                    acc[ms][ns] = __builtin_amdgcn_mfma_f32_16x16x32_bf16(
                        af[ms][h], bf[ns][h], acc[ms][ns], 0, 0, 0);
        __builtin_amdgcn_s_setprio(0);

        if (it < 7) write_stage(cur ^ 1);
        cur ^= 1;
    }

    if (n0 < 512) {
        #pragma unroll
        for (int ns = 0; ns < 2; ++ns) {
            const int col = n0 + wn * 32 + ns * 16 + lr;
            const float bv = bq[col];
            #pragma unroll
            for (int ms = 0; ms < 2; ++ms) {
                const int row = m0 + wm * 32 + ms * 16 + lg * 4;
                #pragma unroll
                for (int j = 0; j < 4; ++j)
                    qb[(size_t)(row + j) * DIMC + col] = f2bf(acc[ms][ns][j] + bv);
            }
        }
    } else {
        #pragma unroll
        for (int ns = 0; ns < 2; ++ns) {
            const int col = n0 - 512 + wn * 32 + ns * 16 + lr;
            const float bv = bkv[col];
            #pragma unroll
            for (int ms = 0; ms < 2; ++ms) {
                const int row = m0 + wm * 32 + ms * 16 + lg * 4;
                #pragma unroll
                for (int j = 0; j < 4; ++j)
                    kvb[(size_t)(row + j) * 1024 + col] = f2bf(acc[ms][ns][j] + bv);
            }
        }
    }
}

// ------- depthwise 3x3 s2 SAME, bf16 in -> K [b][2048][64], V^T [b][64][2048]
__global__ __launch_bounds__(256) void dwconv_k(
    const short* __restrict__ kvb, const float* __restrict__ kern,
    const float* __restrict__ dbias, short* __restrict__ Kbf,
    short* __restrict__ Vt)
{
    int idx = blockIdx.x * 256 + threadIdx.x;
    const int c  = idx & 1023;
    const int ow = (idx >> 10) & 15;
    const int oh = (idx >> 14) & 15;
    const int b  = idx >> 18;
    float acc = dbias[c];
    #pragma unroll
    for (int kh = 0; kh < 3; ++kh) {
        int ih = oh * 2 + kh;
        if (ih >= Hh) continue;
        #pragma unroll
        for (int kw = 0; kw < 3; ++kw) {
            int iw = ow * 2 + kw;
            if (iw >= Ww) continue;
            acc += bf2f(kvb[(((size_t)b * Hh + ih) * Ww + iw) * 1024 + c])
                 * kern[(kh * 3 + kw) * 1024 + c];
        }
    }
    const int s = oh * KVW + ow;
    if (c < 512) {
        int d = c & 63, ck = c >> 6;
        Kbf[((size_t)b * Mkv + s * 8 + ck) * HD + d] = f2bf(acc);
    } else {
        int c2 = c - 512;
        int d = c2 & 63, ck = c2 >> 6;
        Vt[((size_t)b * HD + d) * Mkv + s * 8 + ck] = f2bf(acc);
    }
}

// ---------------- flash attention, split-m (NC=4), fixed m=0 ---------------
// po written in OUTPUT layout [chunk][2048 tok][512 ch] (normalized o/l);
// pl [chunk][NROWS] row sums. Combine happens in gemm_out's A-staging.
__global__ __launch_bounds__(128) void attn_mfma_k(
    const short* __restrict__ qb, const short* __restrict__ K,
    const short* __restrict__ Vt, short* __restrict__ po,
    float* __restrict__ pl)
{
    __shared__ __align__(16) char smem[20480];
    char* Kl = smem;
    char* Vl = smem + 8192;
    const int tid  = threadIdx.x;
    const int w    = tid >> 6;
    const int lane = tid & 63;
    char* Pl = smem + 16384 + w * 2048;
    const int bid = blockIdx.x;           // 512
    const int chunk = blockIdx.y;         // 0..NC-1
    const int qt  = bid & 31;
    const int n   = (bid >> 5) & 7;
    const int b   = bid >> 8;
    const int q0  = qt * QTILE + w * 16;
    const int lr = lane & 15;
    const int lg = lane >> 4;

    bf16x8_t qf[2];
    {
        const short* qrow = qb + ((size_t)(b * Lq) + q0 + lr) * DIMC + n * HD + lg * 8;
        #pragma unroll
        for (int ks = 0; ks < 2; ++ks) {
            bf16x8_t t = *reinterpret_cast<const bf16x8_t*>(qrow + ks * 32);
            #pragma unroll
            for (int j = 0; j < 8; ++j) t[j] = f2bf(bf2f(t[j]) * SL2E);
            qf[ks] = t;
        }
    }

    f32x4_t o[4];
    #pragma unroll
    for (int dt = 0; dt < 4; ++dt) o[dt] = f32x4_t{0.f,0.f,0.f,0.f};
    float lacc[4] = {0.f,0.f,0.f,0.f};

    const short* Kb = K  + (size_t)b * Mkv * HD;
    const short* Vb = Vt + (size_t)b * HD * Mkv;
    const int mbase = chunk * (Mkv / NC);

    const int Lr8 = lane >> 3;
    const int jj  = lane & 7;
    bf16x8_t kreg[4], vreg[4];
    auto load_tile = [&](int mt) {
        #pragma unroll
        for (int c = 0; c < 4; ++c) {
            const int row = c * 16 + w * 8 + Lr8;
            kreg[c] = *reinterpret_cast<const bf16x8_t*>(
                Kb + (size_t)(mt + row) * HD + jj * 8);
            vreg[c] = *reinterpret_cast<const bf16x8_t*>(
                Vb + (size_t)row * Mkv + mt + jj * 8);
        }
    };
    auto write_tile = [&]() {
        #pragma unroll
        for (int c = 0; c < 4; ++c) {
            const int row = c * 16 + w * 8 + Lr8;
            const int off = row * 128 + ((jj * 16) ^ ((row & 7) << 4));
            *reinterpret_cast<bf16x8_t*>(Kl + off) = kreg[c];
            *reinterpret_cast<bf16x8_t*>(Vl + off) = vreg[c];
        }
    };

    load_tile(mbase);
    for (int it = 0; it < ITERS; ++it) {
        write_tile();
        __syncthreads();
        if (it < ITERS - 1) load_tile(mbase + (it + 1) * MTILE);

        f32x4_t s[4];
        __builtin_amdgcn_s_setprio(1);
        #pragma unroll
        for (int nt = 0; nt < 4; ++nt) {
            const int ml = nt * 16 + lr;
            f32x4_t acc = f32x4_t{0.f,0.f,0.f,0.f};
            bf16x8_t k0 = *reinterpret_cast<bf16x8_t*>(
                Kl + ml * 128 + ((lg * 16)      ^ ((ml & 7) << 4)));
            bf16x8_t k1 = *reinterpret_cast<bf16x8_t*>(
                Kl + ml * 128 + ((64 + lg * 16) ^ ((ml & 7) << 4)));
            acc = __builtin_amdgcn_mfma_f32_16x16x32_bf16(qf[0], k0, acc, 0,0,0);
            acc = __builtin_amdgcn_mfma_f32_16x16x32_bf16(qf[1], k1, acc, 0,0,0);
            s[nt] = acc;
        }
        __builtin_amdgcn_s_setprio(0);
        #pragma unroll
        for (int nt = 0; nt < 4; ++nt)
            #pragma unroll
            for (int r = 0; r < 4; ++r) {
                float p = exp2f(s[nt][r]);
                s[nt][r] = p;
                lacc[r] += p;
            }

        #pragma unroll
        for (int nt = 0; nt < 4; ++nt)
            #pragma unroll
            for (int r = 0; r < 4; ++r) {
                const int qL = lg * 4 + r;
                const int mL = nt * 16 + lr;
                *reinterpret_cast<short*>(
                    Pl + qL * 128 + ((mL * 2) ^ ((qL & 7) << 4))) = f2bf(s[nt][r]);
            }

        bf16x8_t pf[2];
        #pragma unroll
        for (int ks2 = 0; ks2 < 2; ++ks2)
            pf[ks2] = *reinterpret_cast<bf16x8_t*>(
                Pl + lr * 128 + ((ks2 * 64 + lg * 16) ^ ((lr & 7) << 4)));
        __builtin_amdgcn_s_setprio(1);
        #pragma unroll
        for (int dt = 0; dt < 4; ++dt) {
            const int dL = dt * 16 + lr;
            #pragma unroll
            for (int ks2 = 0; ks2 < 2; ++ks2) {
                bf16x8_t vb = *reinterpret_cast<bf16x8_t*>(
                    Vl + dL * 128 + ((ks2 * 64 + lg * 16) ^ ((dL & 7) << 4)));
                o[dt] = __builtin_amdgcn_mfma_f32_16x16x32_bf16(pf[ks2], vb, o[dt], 0,0,0);
            }
        }
        __builtin_amdgcn_s_setprio(0);
        __syncthreads();
    }

    #pragma unroll
    for (int r = 0; r < 4; ++r) {
        float l = lacc[r];
        l += __shfl_xor(l, 1);
        l += __shfl_xor(l, 2);
        l += __shfl_xor(l, 4);
        l += __shfl_xor(l, 8);
        const float inv = 1.0f / l;
        const int tok = (b << 10) + q0 + lg * 4 + r;           // 0..2047
        #pragma unroll
        for (int dt = 0; dt < 4; ++dt)
            po[((size_t)chunk * BHW + tok) * DIMC + (n << 6) + dt * 16 + lr] =
                f2bf(o[dt][r] * inv);
        if (lr == 0)
            pl[chunk * NROWS + ((b * NHEADS + n) << 10) + q0 + lg * 4 + r] = l;
    }
}

// ------- out GEMM, LDS-tiled 32x64 + fused combine in A-staging ------------
// grid (8, 64); 4 waves of 16x32; BK=64; double-buffered swizzled LDS.
// A[m][k] = sum_c l_c * po[c][m][k] / sum_c l_c   (bf16, staged to LDS)
__global__ __launch_bounds__(256) void gemm_out_k(
    const short* __restrict__ po, const float* __restrict__ pl,
    const short* __restrict__ WT, const float* __restrict__ bo,
    float* __restrict__ C)
{
    __shared__ __align__(16) char smem[24576];   // [buf][A 4K | B 8K]
    const int tid = threadIdx.x, w = tid >> 6, lane = tid & 63;
    const int lr = lane & 15, lg = lane >> 4;
    const int wm = w >> 1, wn = w & 1;
    const int m0 = blockIdx.y * 32;
    const int n0 = blockIdx.x * 64;

    // A staging: row sr (0..31), 8-elem group scA (0..7)
    const int sr = tid >> 3, scA = tid & 7;
    const int m  = m0 + sr;
    // B staging: row srB (0..63), 16-elem group scB (0..3)
    const int srB = tid >> 2, scB = tid & 3;
    const short* Bsrc = WT + (size_t)(n0 + srB) * DIMC + scB * 16;

    bf16x8_t pr[NC]; float lv[NC]; bf16x8_t br[2];
    auto load_stage = [&](int kc) {
        const int kg = kc + scA * 8;
        const int hn = kg >> 6;                         // head of this k-group
        const int grow = ((m >> 10) * NHEADS + hn) * 1024 + (m & 1023);
        #pragma unroll
        for (int c = 0; c < NC; ++c) {
            pr[c] = *reinterpret_cast<const bf16x8_t*>(
                po + ((size_t)c * BHW + m) * DIMC + kg);
            lv[c] = pl[c * NROWS + grow];
        }
        br[0] = *reinterpret_cast<const bf16x8_t*>(Bsrc + kc);
        br[1] = *reinterpret_cast<const bf16x8_t*>(Bsrc + kc + 8);
    };
    auto write_stage = [&](int bb) {
        char* S = smem + bb * 12288;
        const float inv = 1.0f / (lv[0] + lv[1] + lv[2] + lv[3]);
        bf16x8_t av;
        #pragma unroll
        for (int j = 0; j < 8; ++j) {
            float s = lv[0]*bf2f(pr[0][j]) + lv[1]*bf2f(pr[1][j])
                    + lv[2]*bf2f(pr[2][j]) + lv[3]*bf2f(pr[3][j]);
            av[j] = f2bf(s * inv);
        }
        *reinterpret_cast<bf16x8_t*>(
            S + sr * 128 + ((scA * 16) ^ ((sr & 7) << 4))) = av;
        *reinterpret_cast<bf16x8_t*>(
            S + 4096 + srB * 128 + ((scB * 32)      ^ ((srB & 7) << 4))) = br[0];
        *reinterpret_cast<bf16x8_t*>(
            S + 4096 + srB * 128 + ((scB * 32 + 16) ^ ((srB & 7) << 4))) = br[1];
    };

    f32x4_t acc[2];
    acc[0] = f32x4_t{0.f,0.f,0.f,0.f};
    acc[1] = f32x4_t{0.f,0.f,0.f,0.f};

    load_stage(0);
    write_stage(0);
    int cur = 0;

    for (int it = 0; it < 8; ++it) {
        __syncthreads();
        if (it < 7) load_stage((it + 1) * 64);

        char* S = smem + cur * 12288;
        const int arow = wm * 16 + lr;
        bf16x8_t af[2], bfr[2][2];
        #pragma unroll
        for (int h = 0; h < 2; ++h) {
            af[h] = *reinterpret_cast<bf16x8_t*>(
                S + arow * 128 + ((h*64 + lg*16) ^ ((arow & 7) << 4)));
            #pragma unroll
            for (int ns = 0; ns < 2; ++ns) {
                const int brow = wn * 32 + ns * 16 + lr;
                bfr[ns][h] = *reinterpret_cast<bf16x8_t*>(
                    S + 4096 + brow * 128 + ((h*64 + lg*16) ^ ((brow & 7) << 4)));
            }
        }
        __builtin_amdgcn_s_setprio(1);
        #pragma unroll
        for (int ns = 0; ns < 2; ++ns)
            #pragma unroll
            for (int h = 0; h < 2; ++h)
                acc[ns] = __builtin_amdgcn_mfma_f32_16x16x32_bf16(
                    af[h], bfr[ns][h], acc[ns], 0, 0, 0);
        __builtin_amdgcn_s_setprio(0);

        if (it < 7) write_stage(cur ^ 1);
        cur ^= 1;
    }

    #pragma unroll
    for (int ns = 0; ns < 2; ++ns) {
        const int col = n0 + wn * 32 + ns * 16 + lr;
        const float bv = bo[col];
        const int row = m0 + wm * 16 + lg * 4;
        #pragma unroll
        for (int j = 0; j < 4; ++j)
            C[(size_t)(row + j) * DIMC + col] = acc[ns][j] + bv;
    }
}

extern "C" void kernel_launch(void* const* d_in, const int* in_sizes, int n_in,
                              void* d_out, int out_size, void* d_ws, size_t ws_size,
                              hipStream_t stream)
{
    const float* x    = (const float*)d_in[0];
    const float* wq   = (const float*)d_in[1];
    const float* bq   = (const float*)d_in[2];
    const float* wkv  = (const float*)d_in[3];
    const float* bkv  = (const float*)d_in[4];
    const float* dwk  = (const float*)d_in[5];
    const float* dwb  = (const float*)d_in[6];
    const float* wo   = (const float*)d_in[7];
    const float* bo   = (const float*)d_in[8];
    float* out = (float*)d_out;

    // scratch region (first 8.7 MB): po/pl overlay kvb+xb (dead before attn)
    short* po    = (short*)d_ws;                          // 4*2048*512 bf16 (8.4MB)
    float* pl    = (float*)(po + (size_t)NC * BHW * DIMC);// 4*16384 f32
    short* kvb   = (short*)d_ws;                          // 2048*1024 bf16 (overlay)
    short* xb    = kvb + (size_t)BHW * 1024;              // 2048*512 bf16 (overlay)
    // persistent (after pl)
    short* wqkvT = (short*)(pl + (size_t)NC * NROWS);     // 1536*512
    short* woT   = wqkvT + (size_t)3 * DIMC * DIMC;       // 512*512
    short* qb    = woT   + (size_t)DIMC * DIMC;           // 2048*512
    short* Kbf   = qb    + (size_t)BHW * DIMC;            // 2*2048*64
    short* Vt    = Kbf   + (size_t)Bb * Mkv * HD;         // 2*64*2048

    prep_k<<<dim3(32, 16, 4), 256, 0, stream>>>(x, xb, wq, wkv, wo, wqkvT, woT);

    gemm_qkv_k<<<dim3(24, 32), 256, 0, stream>>>(xb, wqkvT, bq, bkv, qb, kvb);

    dwconv_k<<<(Bb * KVH * KVW * 1024) / 256, 256, 0, stream>>>(
        kvb, dwk, dwb, Kbf, Vt);

    attn_mfma_k<<<dim3(Bb * NHEADS * (Lq / QTILE), NC), 128, 0, stream>>>(
        qb, Kbf, Vt, po, pl);

    gemm_out_k<<<dim3(8, 64), 256, 0, stream>>>(po, pl, woT, bo, out);
}

// Round 13
// 62.077 us; speedup vs baseline: 6.4083x; 1.0970x over previous
//
#include <hip/hip_runtime.h>
#include <hip/hip_bf16.h>

#define DIMC   512
#define NHEADS 8
#define HD     64
#define Bb     2
#define Hh     32
#define Ww     32
#define Lq     1024          // H*W
#define BHW    2048          // B*H*W
#define KVH    16
#define KVW    16
#define Mkv    2048          // KVH*KVW*NHEADS
#define SL2E   0.18033688011112042f   // (1/8) * log2(e)
#define NC     4             // attention m-chunks (split-K)
#define NROWS  (Bb * NHEADS * Lq)     // 16384 partial rows

typedef short bf16x8_t __attribute__((ext_vector_type(8)));
typedef float f32x4_t  __attribute__((ext_vector_type(4)));

__device__ __forceinline__ short f2bf(float f) {
    __hip_bfloat16 h = __float2bfloat16(f);
    return *reinterpret_cast<short*>(&h);
}
__device__ __forceinline__ float bf2f(short s) {
    unsigned u = ((unsigned)(unsigned short)s) << 16;
    return *reinterpret_cast<float*>(&u);
}

#define QTILE 64
#define MTILE 64
#define ITERS (Mkv / NC / MTILE)   // 8

// ------- prep: cast x -> bf16 (z=0) + transpose wq/wkv/wo (z=1..3) ---------
__global__ __launch_bounds__(256) void prep_k(
    const float* __restrict__ x, short* __restrict__ xb,
    const float* __restrict__ wq, const float* __restrict__ wkv,
    const float* __restrict__ wo, short* __restrict__ wqkvT,
    short* __restrict__ woT)
{
    const int z = blockIdx.z;
    if (z == 0) {
        const int i = (blockIdx.y * 32 + blockIdx.x) * 256 + threadIdx.x;
        const float4 f0 = reinterpret_cast<const float4*>(x)[i * 2 + 0];
        const float4 f1 = reinterpret_cast<const float4*>(x)[i * 2 + 1];
        bf16x8_t t;
        t[0]=f2bf(f0.x); t[1]=f2bf(f0.y); t[2]=f2bf(f0.z); t[3]=f2bf(f0.w);
        t[4]=f2bf(f1.x); t[5]=f2bf(f1.y); t[6]=f2bf(f1.z); t[7]=f2bf(f1.w);
        reinterpret_cast<bf16x8_t*>(xb)[i] = t;
        return;
    }
    const float* W; short* WT; int N, rbase;
    if (z == 1)      { W = wq;  WT = wqkvT; N = DIMC;     rbase = 0;   }
    else if (z == 2) { W = wkv; WT = wqkvT; N = 2 * DIMC; rbase = 512; }
    else             { W = wo;  WT = woT;   N = DIMC;     rbase = 0;   }
    const int n0 = blockIdx.x * 32, k0 = blockIdx.y * 32;
    if (n0 >= N) return;
    __shared__ float t[32][33];
    const int c = threadIdx.x & 31, r = threadIdx.x >> 5;   // r 0..7
    #pragma unroll
    for (int i = 0; i < 4; ++i)
        t[r + 8 * i][c] = W[(size_t)(k0 + r + 8 * i) * N + n0 + c];
    __syncthreads();
    #pragma unroll
    for (int i = 0; i < 4; ++i)
        WT[(size_t)(rbase + n0 + r + 8 * i) * DIMC + k0 + c] = f2bf(t[c][r + 8 * i]);
}

// ------- LDS-tiled q/kv GEMM: xb[2048,512] @ wqkvT[1536,512]^T -------------
// block 64x64, 4 waves (2x2 of 32x32), BK=64, double-buffered LDS (swizzled).
__global__ __launch_bounds__(256) void gemm_qkv_k(
    const short* __restrict__ A, const short* __restrict__ WT,
    const float* __restrict__ bq, const float* __restrict__ bkv,
    short* __restrict__ qb, short* __restrict__ kvb)
{
    __shared__ __align__(16) char smem[32768];   // [buf][A 8K | B 8K]
    const int tid = threadIdx.x, w = tid >> 6, lane = tid & 63;
    const int lr = lane & 15, lg = lane >> 4;
    const int wm = w >> 1, wn = w & 1;
    const int m0 = blockIdx.y * 64;
    const int n0 = blockIdx.x * 64;

    const int sr = tid >> 2, sc = tid & 3;
    const short* Asrc = A  + (size_t)(m0 + sr) * DIMC + sc * 16;
    const short* Bsrc = WT + (size_t)(n0 + sr) * DIMC + sc * 16;
    bf16x8_t ar[2], br[2];
    auto load_stage = [&](int kc) {
        ar[0] = *reinterpret_cast<const bf16x8_t*>(Asrc + kc);
        ar[1] = *reinterpret_cast<const bf16x8_t*>(Asrc + kc + 8);
        br[0] = *reinterpret_cast<const bf16x8_t*>(Bsrc + kc);
        br[1] = *reinterpret_cast<const bf16x8_t*>(Bsrc + kc + 8);
    };
    const int rowb = sr * 128;
    const int swzw = (sr & 7) << 4;
    auto write_stage = [&](int bb) {
        char* S = smem + bb * 16384;
        *reinterpret_cast<bf16x8_t*>(S +        rowb + ((sc*32     ) ^ swzw)) = ar[0];
        *reinterpret_cast<bf16x8_t*>(S +        rowb + ((sc*32 + 16) ^ swzw)) = ar[1];
        *reinterpret_cast<bf16x8_t*>(S + 8192 + rowb + ((sc*32     ) ^ swzw)) = br[0];
        *reinterpret_cast<bf16x8_t*>(S + 8192 + rowb + ((sc*32 + 16) ^ swzw)) = br[1];
    };

    f32x4_t acc[2][2];
    #pragma unroll
    for (int i = 0; i < 2; ++i)
        #pragma unroll
        for (int j = 0; j < 2; ++j) acc[i][j] = f32x4_t{0.f,0.f,0.f,0.f};

    load_stage(0);
    write_stage(0);
    int cur = 0;

    for (int it = 0; it < 8; ++it) {
        __syncthreads();
        if (it < 7) load_stage((it + 1) * 64);

        char* S = smem + cur * 16384;
        bf16x8_t af[2][2], bf[2][2];
        #pragma unroll
        for (int s = 0; s < 2; ++s) {
            const int arow = wm * 32 + s * 16 + lr;
            const int brow = wn * 32 + s * 16 + lr;
            #pragma unroll
            for (int h = 0; h < 2; ++h) {
                af[s][h] = *reinterpret_cast<bf16x8_t*>(
                    S +        arow * 128 + ((h*64 + lg*16) ^ ((arow & 7) << 4)));
                bf[s][h] = *reinterpret_cast<bf16x8_t*>(
                    S + 8192 + brow * 128 + ((h*64 + lg*16) ^ ((brow & 7) << 4)));
            }
        }
        __builtin_amdgcn_s_setprio(1);
        #pragma unroll
        for (int ms = 0; ms < 2; ++ms)
            #pragma unroll
            for (int ns = 0; ns < 2; ++ns)
                #pragma unroll
                for (int h = 0; h < 2; ++h)
                    acc[ms][ns] = __builtin_amdgcn_mfma_f32_16x16x32_bf16(
                        af[ms][h], bf[ns][h], acc[ms][ns], 0, 0, 0);
        __builtin_amdgcn_s_setprio(0);

        if (it < 7) write_stage(cur ^ 1);
        cur ^= 1;
    }

    if (n0 < 512) {
        #pragma unroll
        for (int ns = 0; ns < 2; ++ns) {
            const int col = n0 + wn * 32 + ns * 16 + lr;
            const float bv = bq[col];
            #pragma unroll
            for (int ms = 0; ms < 2; ++ms) {
                const int row = m0 + wm * 32 + ms * 16 + lg * 4;
                #pragma unroll
                for (int j = 0; j < 4; ++j)
                    qb[(size_t)(row + j) * DIMC + col] = f2bf(acc[ms][ns][j] + bv);
            }
        }
    } else {
        #pragma unroll
        for (int ns = 0; ns < 2; ++ns) {
            const int col = n0 - 512 + wn * 32 + ns * 16 + lr;
            const float bv = bkv[col];
            #pragma unroll
            for (int ms = 0; ms < 2; ++ms) {
                const int row = m0 + wm * 32 + ms * 16 + lg * 4;
                #pragma unroll
                for (int j = 0; j < 4; ++j)
                    kvb[(size_t)(row + j) * 1024 + col] = f2bf(acc[ms][ns][j] + bv);
            }
        }
    }
}

// ------- depthwise 3x3 s2 SAME, bf16 in -> K [b][2048][64], V^T [b][64][2048]
__global__ __launch_bounds__(256) void dwconv_k(
    const short* __restrict__ kvb, const float* __restrict__ kern,
    const float* __restrict__ dbias, short* __restrict__ Kbf,
    short* __restrict__ Vt)
{
    int idx = blockIdx.x * 256 + threadIdx.x;
    const int c  = idx & 1023;
    const int ow = (idx >> 10) & 15;
    const int oh = (idx >> 14) & 15;
    const int b  = idx >> 18;
    float acc = dbias[c];
    #pragma unroll
    for (int kh = 0; kh < 3; ++kh) {
        int ih = oh * 2 + kh;
        if (ih >= Hh) continue;
        #pragma unroll
        for (int kw = 0; kw < 3; ++kw) {
            int iw = ow * 2 + kw;
            if (iw >= Ww) continue;
            acc += bf2f(kvb[(((size_t)b * Hh + ih) * Ww + iw) * 1024 + c])
                 * kern[(kh * 3 + kw) * 1024 + c];
        }
    }
    const int s = oh * KVW + ow;
    if (c < 512) {
        int d = c & 63, ck = c >> 6;
        Kbf[((size_t)b * Mkv + s * 8 + ck) * HD + d] = f2bf(acc);
    } else {
        int c2 = c - 512;
        int d = c2 & 63, ck = c2 >> 6;
        Vt[((size_t)b * HD + d) * Mkv + s * 8 + ck] = f2bf(acc);
    }
}

// ---------------- flash attention, split-m (NC=4), fixed m=0 ---------------
// QTILE=64: 4 waves share each K/V tile (halves staging traffic);
// double-buffered K/V LDS -> 1 barrier/iter. po in output layout.
__global__ __launch_bounds__(256) void attn_mfma_k(
    const short* __restrict__ qb, const short* __restrict__ K,
    const short* __restrict__ Vt, short* __restrict__ po,
    float* __restrict__ pl)
{
    __shared__ __align__(16) char smem[40960];  // 2 x (K 8K | V 8K) + 4 x P 2K
    const int tid  = threadIdx.x;
    const int w    = tid >> 6;
    const int lane = tid & 63;
    char* Pl = smem + 32768 + w * 2048;
    const int bid = blockIdx.x;           // 256
    const int chunk = blockIdx.y;         // 0..NC-1
    const int qt  = bid & 15;
    const int n   = (bid >> 4) & 7;
    const int b   = bid >> 7;
    const int q0  = qt * QTILE + w * 16;
    const int lr = lane & 15;
    const int lg = lane >> 4;

    // Q fragments, pre-scaled by SL2E
    bf16x8_t qf[2];
    {
        const short* qrow = qb + ((size_t)(b * Lq) + q0 + lr) * DIMC + n * HD + lg * 8;
        #pragma unroll
        for (int ks = 0; ks < 2; ++ks) {
            bf16x8_t t = *reinterpret_cast<const bf16x8_t*>(qrow + ks * 32);
            #pragma unroll
            for (int j = 0; j < 8; ++j) t[j] = f2bf(bf2f(t[j]) * SL2E);
            qf[ks] = t;
        }
    }

    f32x4_t o[4];
    #pragma unroll
    for (int dt = 0; dt < 4; ++dt) o[dt] = f32x4_t{0.f,0.f,0.f,0.f};
    float lacc[4] = {0.f,0.f,0.f,0.f};

    const short* Kb = K  + (size_t)b * Mkv * HD;
    const short* Vb = Vt + (size_t)b * HD * Mkv;
    const int mbase = chunk * (Mkv / NC);

    // staging: 256 threads, row sr 0..63, chunks jc and jc+4
    const int sr = tid >> 2;
    const int jc = tid & 3;
    bf16x8_t kreg[2], vreg[2];
    auto load_tile = [&](int mt) {
        #pragma unroll
        for (int i = 0; i < 2; ++i) {
            kreg[i] = *reinterpret_cast<const bf16x8_t*>(
                Kb + (size_t)(mt + sr) * HD + (jc + 4 * i) * 8);
            vreg[i] = *reinterpret_cast<const bf16x8_t*>(
                Vb + (size_t)sr * Mkv + mt + (jc + 4 * i) * 8);
        }
    };
    auto write_tile = [&](int bb) {
        char* Kl = smem + bb * 16384;
        char* Vl = smem + bb * 16384 + 8192;
        #pragma unroll
        for (int i = 0; i < 2; ++i) {
            const int off = sr * 128 + ((((jc + 4 * i) * 16)) ^ ((sr & 7) << 4));
            *reinterpret_cast<bf16x8_t*>(Kl + off) = kreg[i];
            *reinterpret_cast<bf16x8_t*>(Vl + off) = vreg[i];
        }
    };

    load_tile(mbase);
    write_tile(0);
    int cur = 0;

    for (int it = 0; it < ITERS; ++it) {
        __syncthreads();                          // buf[cur] ready
        if (it < ITERS - 1) load_tile(mbase + (it + 1) * MTILE);

        char* Kl = smem + cur * 16384;
        char* Vl = smem + cur * 16384 + 8192;

        f32x4_t s[4];
        __builtin_amdgcn_s_setprio(1);
        #pragma unroll
        for (int nt = 0; nt < 4; ++nt) {
            const int ml = nt * 16 + lr;
            f32x4_t acc = f32x4_t{0.f,0.f,0.f,0.f};
            bf16x8_t k0 = *reinterpret_cast<bf16x8_t*>(
                Kl + ml * 128 + ((lg * 16)      ^ ((ml & 7) << 4)));
            bf16x8_t k1 = *reinterpret_cast<bf16x8_t*>(
                Kl + ml * 128 + ((64 + lg * 16) ^ ((ml & 7) << 4)));
            acc = __builtin_amdgcn_mfma_f32_16x16x32_bf16(qf[0], k0, acc, 0,0,0);
            acc = __builtin_amdgcn_mfma_f32_16x16x32_bf16(qf[1], k1, acc, 0,0,0);
            s[nt] = acc;
        }
        __builtin_amdgcn_s_setprio(0);
        #pragma unroll
        for (int nt = 0; nt < 4; ++nt)
            #pragma unroll
            for (int r = 0; r < 4; ++r) {
                float p = exp2f(s[nt][r]);
                s[nt][r] = p;
                lacc[r] += p;
            }

        // P -> per-wave LDS (wave-local; DS in-order: no barrier)
        #pragma unroll
        for (int nt = 0; nt < 4; ++nt)
            #pragma unroll
            for (int r = 0; r < 4; ++r) {
                const int qL = lg * 4 + r;
                const int mL = nt * 16 + lr;
                *reinterpret_cast<short*>(
                    Pl + qL * 128 + ((mL * 2) ^ ((qL & 7) << 4))) = f2bf(s[nt][r]);
            }

        bf16x8_t pf[2];
        #pragma unroll
        for (int ks2 = 0; ks2 < 2; ++ks2)
            pf[ks2] = *reinterpret_cast<bf16x8_t*>(
                Pl + lr * 128 + ((ks2 * 64 + lg * 16) ^ ((lr & 7) << 4)));
        __builtin_amdgcn_s_setprio(1);
        #pragma unroll
        for (int dt = 0; dt < 4; ++dt) {
            const int dL = dt * 16 + lr;
            #pragma unroll
            for (int ks2 = 0; ks2 < 2; ++ks2) {
                bf16x8_t vb = *reinterpret_cast<bf16x8_t*>(
                    Vl + dL * 128 + ((ks2 * 64 + lg * 16) ^ ((dL & 7) << 4)));
                o[dt] = __builtin_amdgcn_mfma_f32_16x16x32_bf16(pf[ks2], vb, o[dt], 0,0,0);
            }
        }
        __builtin_amdgcn_s_setprio(0);

        if (it < ITERS - 1) write_tile(cur ^ 1);  // safe: all waves passed barrier
        cur ^= 1;
    }

    #pragma unroll
    for (int r = 0; r < 4; ++r) {
        float l = lacc[r];
        l += __shfl_xor(l, 1);
        l += __shfl_xor(l, 2);
        l += __shfl_xor(l, 4);
        l += __shfl_xor(l, 8);
        const float inv = 1.0f / l;
        const int tok = (b << 10) + q0 + lg * 4 + r;           // 0..2047
        #pragma unroll
        for (int dt = 0; dt < 4; ++dt)
            po[((size_t)chunk * BHW + tok) * DIMC + (n << 6) + dt * 16 + lr] =
                f2bf(o[dt][r] * inv);
        if (lr == 0)
            pl[chunk * NROWS + ((b * NHEADS + n) << 10) + q0 + lg * 4 + r] = l;
    }
}

// ------- out GEMM, LDS-tiled 32x64 + fused combine in A-staging ------------
__global__ __launch_bounds__(256) void gemm_out_k(
    const short* __restrict__ po, const float* __restrict__ pl,
    const short* __restrict__ WT, const float* __restrict__ bo,
    float* __restrict__ C)
{
    __shared__ __align__(16) char smem[24576];   // [buf][A 4K | B 8K]
    const int tid = threadIdx.x, w = tid >> 6, lane = tid & 63;
    const int lr = lane & 15, lg = lane >> 4;
    const int wm = w >> 1, wn = w & 1;
    const int m0 = blockIdx.y * 32;
    const int n0 = blockIdx.x * 64;

    const int sr = tid >> 3, scA = tid & 7;
    const int m  = m0 + sr;
    const int srB = tid >> 2, scB = tid & 3;
    const short* Bsrc = WT + (size_t)(n0 + srB) * DIMC + scB * 16;

    bf16x8_t pr[NC]; float lv[NC]; bf16x8_t br[2];
    auto load_stage = [&](int kc) {
        const int kg = kc + scA * 8;
        const int hn = kg >> 6;
        const int grow = ((m >> 10) * NHEADS + hn) * 1024 + (m & 1023);
        #pragma unroll
        for (int c = 0; c < NC; ++c) {
            pr[c] = *reinterpret_cast<const bf16x8_t*>(
                po + ((size_t)c * BHW + m) * DIMC + kg);
            lv[c] = pl[c * NROWS + grow];
        }
        br[0] = *reinterpret_cast<const bf16x8_t*>(Bsrc + kc);
        br[1] = *reinterpret_cast<const bf16x8_t*>(Bsrc + kc + 8);
    };
    auto write_stage = [&](int bb) {
        char* S = smem + bb * 12288;
        const float inv = 1.0f / (lv[0] + lv[1] + lv[2] + lv[3]);
        bf16x8_t av;
        #pragma unroll
        for (int j = 0; j < 8; ++j) {
            float s = lv[0]*bf2f(pr[0][j]) + lv[1]*bf2f(pr[1][j])
                    + lv[2]*bf2f(pr[2][j]) + lv[3]*bf2f(pr[3][j]);
            av[j] = f2bf(s * inv);
        }
        *reinterpret_cast<bf16x8_t*>(
            S + sr * 128 + ((scA * 16) ^ ((sr & 7) << 4))) = av;
        *reinterpret_cast<bf16x8_t*>(
            S + 4096 + srB * 128 + ((scB * 32)      ^ ((srB & 7) << 4))) = br[0];
        *reinterpret_cast<bf16x8_t*>(
            S + 4096 + srB * 128 + ((scB * 32 + 16) ^ ((srB & 7) << 4))) = br[1];
    };

    f32x4_t acc[2];
    acc[0] = f32x4_t{0.f,0.f,0.f,0.f};
    acc[1] = f32x4_t{0.f,0.f,0.f,0.f};

    load_stage(0);
    write_stage(0);
    int cur = 0;

    for (int it = 0; it < 8; ++it) {
        __syncthreads();
        if (it < 7) load_stage((it + 1) * 64);

        char* S = smem + cur * 12288;
        const int arow = wm * 16 + lr;
        bf16x8_t af[2], bfr[2][2];
        #pragma unroll
        for (int h = 0; h < 2; ++h) {
            af[h] = *reinterpret_cast<bf16x8_t*>(
                S + arow * 128 + ((h*64 + lg*16) ^ ((arow & 7) << 4)));
            #pragma unroll
            for (int ns = 0; ns < 2; ++ns) {
                const int brow = wn * 32 + ns * 16 + lr;
                bfr[ns][h] = *reinterpret_cast<bf16x8_t*>(
                    S + 4096 + brow * 128 + ((h*64 + lg*16) ^ ((brow & 7) << 4)));
            }
        }
        __builtin_amdgcn_s_setprio(1);
        #pragma unroll
        for (int ns = 0; ns < 2; ++ns)
            #pragma unroll
            for (int h = 0; h < 2; ++h)
                acc[ns] = __builtin_amdgcn_mfma_f32_16x16x32_bf16(
                    af[h], bfr[ns][h], acc[ns], 0, 0, 0);
        __builtin_amdgcn_s_setprio(0);

        if (it < 7) write_stage(cur ^ 1);
        cur ^= 1;
    }

    #pragma unroll
    for (int ns = 0; ns < 2; ++ns) {
        const int col = n0 + wn * 32 + ns * 16 + lr;
        const float bv = bo[col];
        const int row = m0 + wm * 16 + lg * 4;
        #pragma unroll
        for (int j = 0; j < 4; ++j)
            C[(size_t)(row + j) * DIMC + col] = acc[ns][j] + bv;
    }
}

extern "C" void kernel_launch(void* const* d_in, const int* in_sizes, int n_in,
                              void* d_out, int out_size, void* d_ws, size_t ws_size,
                              hipStream_t stream)
{
    const float* x    = (const float*)d_in[0];
    const float* wq   = (const float*)d_in[1];
    const float* bq   = (const float*)d_in[2];
    const float* wkv  = (const float*)d_in[3];
    const float* bkv  = (const float*)d_in[4];
    const float* dwk  = (const float*)d_in[5];
    const float* dwb  = (const float*)d_in[6];
    const float* wo   = (const float*)d_in[7];
    const float* bo   = (const float*)d_in[8];
    float* out = (float*)d_out;

    // scratch region (first 8.7 MB): po/pl overlay kvb+xb (dead before attn)
    short* po    = (short*)d_ws;                          // 4*2048*512 bf16 (8.4MB)
    float* pl    = (float*)(po + (size_t)NC * BHW * DIMC);// 4*16384 f32
    short* kvb   = (short*)d_ws;                          // 2048*1024 bf16 (overlay)
    short* xb    = kvb + (size_t)BHW * 1024;              // 2048*512 bf16 (overlay)
    // persistent (after pl)
    short* wqkvT = (short*)(pl + (size_t)NC * NROWS);     // 1536*512
    short* woT   = wqkvT + (size_t)3 * DIMC * DIMC;       // 512*512
    short* qb    = woT   + (size_t)DIMC * DIMC;           // 2048*512
    short* Kbf   = qb    + (size_t)BHW * DIMC;            // 2*2048*64
    short* Vt    = Kbf   + (size_t)Bb * Mkv * HD;         // 2*64*2048

    prep_k<<<dim3(32, 16, 4), 256, 0, stream>>>(x, xb, wq, wkv, wo, wqkvT, woT);

    gemm_qkv_k<<<dim3(24, 32), 256, 0, stream>>>(xb, wqkvT, bq, bkv, qb, kvb);

    dwconv_k<<<(Bb * KVH * KVW * 1024) / 256, 256, 0, stream>>>(
        kvb, dwk, dwb, Kbf, Vt);

    attn_mfma_k<<<dim3(Bb * NHEADS * (Lq / QTILE), NC), 256, 0, stream>>>(
        qb, Kbf, Vt, po, pl);

    gemm_out_k<<<dim3(8, 64), 256, 0, stream>>>(po, pl, woT, bo, out);
}